// Round 1
// baseline (9085.973 us; speedup 1.0000x reference)
//
#include <hip/hip_runtime.h>
#include <math.h>

#define B_   16
#define L_   1024
#define C_   64
#define D_   512
#define DFF_ 2048
#define TOPK_ 20

constexpr int GBM = 64, GBN = 64, GBK = 16;

typedef float f4 __attribute__((ext_vector_type(4)));

// ---------------------------------------------------------------------------
// Generic f32 GEMM: C[M,N] = op(A[M,K] @ B[K,N] + bias)
// flags bit0: accumulate into C, bit1: exact GELU epilogue
// shiftL>0: A-row circular remap within groups of shiftL rows (for circ conv)
// M,N,K all multiples of tile sizes (guaranteed by caller).
// ---------------------------------------------------------------------------
__global__ __launch_bounds__(256)
void gemm_f32(const float* __restrict__ A, const float* __restrict__ Bm,
              float* __restrict__ Cm, const float* __restrict__ bias,
              int M, int N, int K, int flags, int shift, int shiftL)
{
    __shared__ float As[GBK][GBM + 4];
    __shared__ float Bs[GBK][GBN + 4];
    const int tid = threadIdx.x;
    const int bm = blockIdx.y * GBM;
    const int bn = blockIdx.x * GBN;
    const int tx = tid & 15, ty = tid >> 4;
    const int a_k = tid & 15, a_m0 = tid >> 4;
    const int b_n = tid & 63, b_k0 = tid >> 6;
    float acc[4][4] = {};
    for (int k0 = 0; k0 < K; k0 += GBK) {
#pragma unroll
        for (int r = 0; r < 4; ++r) {
            int m = bm + a_m0 + r * 16;
            int row = m;
            if (shiftL > 0) {
                int l = m & (shiftL - 1);
                int base = m - l;
                l += shift;
                if (l < 0) l += shiftL; else if (l >= shiftL) l -= shiftL;
                row = base + l;
            }
            As[a_k][a_m0 + r * 16] = A[(size_t)row * K + (k0 + a_k)];
        }
#pragma unroll
        for (int r = 0; r < 4; ++r) {
            int kk = b_k0 + r * 4;
            Bs[kk][b_n] = Bm[(size_t)(k0 + kk) * N + (bn + b_n)];
        }
        __syncthreads();
#pragma unroll
        for (int kk = 0; kk < GBK; ++kk) {
            f4 av = *(const f4*)&As[kk][ty * 4];
            f4 bv = *(const f4*)&Bs[kk][tx * 4];
#pragma unroll
            for (int i = 0; i < 4; ++i)
#pragma unroll
                for (int j = 0; j < 4; ++j)
                    acc[i][j] = fmaf(av[i], bv[j], acc[i][j]);
        }
        __syncthreads();
    }
#pragma unroll
    for (int i = 0; i < 4; ++i) {
        int m = bm + ty * 4 + i;
#pragma unroll
        for (int j = 0; j < 4; ++j) {
            int n = bn + tx * 4 + j;
            float c = acc[i][j];
            if (bias) c += bias[n];
            if (flags & 2) c = 0.5f * c * (1.0f + erff(c * 0.70710678118654752f));
            size_t o = (size_t)m * N + n;
            if (flags & 1) Cm[o] += c; else Cm[o] = c;
        }
    }
}

// ---------------------------------------------------------------------------
// Autocorrelation scores: G[b,n] += sum_{t-s == n (mod 1024)} <q_t, k_s>
// One block computes a 64x64 tile of Q*K^T (per batch) and reduces its
// diagonals into G via LDS bins + global atomics. G must be zeroed first.
// ---------------------------------------------------------------------------
__global__ __launch_bounds__(256)
void corr_diag(const float* __restrict__ Q, const float* __restrict__ Km,
               float* __restrict__ G)
{
    __shared__ float Qs[GBK][GBM + 4];
    __shared__ float Ks[GBK][GBN + 4];
    __shared__ float diag[128];
    const int tid = threadIdx.x;
    const int b = blockIdx.z;
    const int bt = blockIdx.y * GBM;
    const int bs = blockIdx.x * GBN;
    const float* Qb = Q + ((size_t)b << 19);
    const float* Kb = Km + ((size_t)b << 19);
    const int tx = tid & 15, ty = tid >> 4;
    const int a_k = tid & 15, a_m0 = tid >> 4;
    float acc[4][4] = {};
    for (int k0 = 0; k0 < 512; k0 += GBK) {
#pragma unroll
        for (int r = 0; r < 4; ++r)
            Qs[a_k][a_m0 + r * 16] = Qb[(size_t)(bt + a_m0 + r * 16) * 512 + k0 + a_k];
#pragma unroll
        for (int r = 0; r < 4; ++r)
            Ks[a_k][a_m0 + r * 16] = Kb[(size_t)(bs + a_m0 + r * 16) * 512 + k0 + a_k];
        __syncthreads();
#pragma unroll
        for (int kk = 0; kk < GBK; ++kk) {
            f4 av = *(const f4*)&Qs[kk][ty * 4];
            f4 bv = *(const f4*)&Ks[kk][tx * 4];
#pragma unroll
            for (int i = 0; i < 4; ++i)
#pragma unroll
                for (int j = 0; j < 4; ++j)
                    acc[i][j] = fmaf(av[i], bv[j], acc[i][j]);
        }
        __syncthreads();
    }
    if (tid < 127) diag[tid] = 0.f;
    __syncthreads();
#pragma unroll
    for (int i = 0; i < 4; ++i)
#pragma unroll
        for (int j = 0; j < 4; ++j) {
            int li = (ty * 4 + i) - (tx * 4 + j) + 63;
            atomicAdd(&diag[li], acc[i][j]);
        }
    __syncthreads();
    if (tid < 127) {
        int n = (bt - bs + tid - 63) & 1023;
        atomicAdd(&G[(b << 10) + n], diag[tid]);
    }
}

// ---------------------------------------------------------------------------
// Per-batch top-20 + softmax over G/512. One block per batch.
// ---------------------------------------------------------------------------
__global__ __launch_bounds__(256)
void topk_kernel(const float* __restrict__ G, int* __restrict__ delay,
                 float* __restrict__ tc)
{
    __shared__ float vals[1024];
    __shared__ float pv[256];
    __shared__ int   pi[256];
    __shared__ float wsel[TOPK_];
    __shared__ int   isel[TOPK_];
    const int b = blockIdx.x, tid = threadIdx.x;
    for (int i = tid; i < 1024; i += 256) vals[i] = G[(b << 10) + i] * (1.0f / 512.0f);
    __syncthreads();
    for (int it = 0; it < TOPK_; ++it) {
        float bv = -INFINITY; int bi = 0;
        for (int i = tid * 4; i < tid * 4 + 4; ++i) {
            float v = vals[i];
            if (v > bv) { bv = v; bi = i; }
        }
        pv[tid] = bv; pi[tid] = bi;
        __syncthreads();
        if (tid == 0) {
            float m = pv[0]; int mi = pi[0];
            for (int t = 1; t < 256; ++t)
                if (pv[t] > m) { m = pv[t]; mi = pi[t]; }
            wsel[it] = m; isel[it] = mi;
            vals[mi] = -INFINITY;
        }
        __syncthreads();
    }
    if (tid == 0) {
        float m = wsel[0];
#pragma unroll
        for (int i = 1; i < TOPK_; ++i) m = fmaxf(m, wsel[i]);
        float e[TOPK_], s = 0.f;
#pragma unroll
        for (int i = 0; i < TOPK_; ++i) { e[i] = expf(wsel[i] - m); s += e[i]; }
        float inv = 1.0f / s;
#pragma unroll
        for (int i = 0; i < TOPK_; ++i) {
            tc[b * TOPK_ + i] = e[i] * inv;
            delay[b * TOPK_ + i] = isel[i];
        }
    }
}

// out[b,l,d] = sum_i tc[b,i] * V[b, (l+delay[b,i]) % 1024, d]
__global__ void agg_kernel(const float* __restrict__ V, const int* __restrict__ delay,
                           const float* __restrict__ tc, float* __restrict__ out)
{
    int idx = blockIdx.x * blockDim.x + threadIdx.x;  // over B*L*D
    int d = idx & 511;
    int l = (idx >> 9) & 1023;
    int b = idx >> 19;
    const float* Vb = V + ((size_t)b << 19);
    float s = 0.f;
#pragma unroll
    for (int i = 0; i < TOPK_; ++i) {
        int dl = delay[b * TOPK_ + i];
        int row = (l + dl) & 1023;
        s += tc[b * TOPK_ + i] * Vb[((size_t)row << 9) + d];
    }
    out[idx] = s;
}

// ---------------------------------------------------------------------------
// series_decomp (moving mean k=25, replicate pad). Thread = (b, seg, ch).
// tmode: 0 seasonal only, 1 also write trend, 2 accumulate trend.
// ---------------------------------------------------------------------------
__global__ void decomp_kernel(const float* __restrict__ x, float* __restrict__ seas,
                              float* __restrict__ trend, int Bn, int Ln, int Ch,
                              int nseg, int tmode)
{
    int idx = blockIdx.x * blockDim.x + threadIdx.x;
    int total = Bn * Ch * nseg;
    if (idx >= total) return;
    int ch = idx % Ch;
    int rest = idx / Ch;
    int seg = rest % nseg;
    int b = rest / nseg;
    int segL = Ln / nseg;
    int l0 = seg * segL;
    const float* xp = x + (size_t)b * Ln * Ch + ch;
    float* sp = seas + (size_t)b * Ln * Ch + ch;
    float* tp = trend ? trend + (size_t)b * Ln * Ch + ch : nullptr;
    float s = 0.f;
    for (int j = -12; j <= 12; ++j) {
        int t = l0 + j;
        t = t < 0 ? 0 : (t > Ln - 1 ? Ln - 1 : t);
        s += xp[(size_t)t * Ch];
    }
    for (int l = l0; l < l0 + segL; ++l) {
        float mm = s * (1.0f / 25.0f);
        sp[(size_t)l * Ch] = xp[(size_t)l * Ch] - mm;
        if (tmode == 1) tp[(size_t)l * Ch] = mm;
        else if (tmode == 2) tp[(size_t)l * Ch] += mm;
        int ta = l + 13; if (ta > Ln - 1) ta = Ln - 1;
        int ts = l - 12; if (ts < 0) ts = 0;
        s += xp[(size_t)ta * Ch] - xp[(size_t)ts * Ch];
    }
}

// x[b,l,d] += sinusoidal pos emb (L=1024, D=512)
__global__ void addpos_kernel(float* __restrict__ x)
{
    int idx = blockIdx.x * blockDim.x + threadIdx.x;  // over B*L*D
    int d = idx & 511;
    int l = (idx >> 9) & 1023;
    int i2 = d & ~1;
    float div = expf(-(float)i2 * 0.017988946039015984f);  // ln(10000)/512
    float ang = (float)l * div;
    x[idx] += (d & 1) ? cosf(ang) : sinf(ang);
}

// LayerNorm over D=512 per row. Block per row (B*L rows).
__global__ __launch_bounds__(256)
void lnrow_kernel(const float* __restrict__ x, const float* __restrict__ g,
                  const float* __restrict__ bv, float* __restrict__ out)
{
    __shared__ float sh1[4], sh2[4];
    int row = blockIdx.x, tid = threadIdx.x;
    const float* xr = x + ((size_t)row << 9);
    float v0 = xr[tid], v1 = xr[tid + 256];
    float s = v0 + v1, q = v0 * v0 + v1 * v1;
#pragma unroll
    for (int o = 32; o > 0; o >>= 1) {
        s += __shfl_down(s, o, 64);
        q += __shfl_down(q, o, 64);
    }
    int wid = tid >> 6;
    if ((tid & 63) == 0) { sh1[wid] = s; sh2[wid] = q; }
    __syncthreads();
    if (tid == 0) {
        sh1[0] = sh1[0] + sh1[1] + sh1[2] + sh1[3];
        sh2[0] = sh2[0] + sh2[1] + sh2[2] + sh2[3];
    }
    __syncthreads();
    float mu = sh1[0] * (1.0f / 512.0f);
    float var = sh2[0] * (1.0f / 512.0f) - mu * mu;
    float inv = rsqrtf(var + 1e-5f);
    out[((size_t)row << 9) + tid] = (v0 - mu) * inv * g[tid] + bv[tid];
    out[((size_t)row << 9) + tid + 256] = (v1 - mu) * inv * g[tid + 256] + bv[tid + 256];
}

// per-(b,d) mean over time of [B,1024,512]
__global__ void colmean_kernel(const float* __restrict__ x, float* __restrict__ m)
{
    int idx = blockIdx.x * blockDim.x + threadIdx.x;
    if (idx >= B_ * D_) return;
    int b = idx >> 9, d = idx & 511;
    const float* xp = x + ((size_t)b << 19) + d;
    float s = 0.f;
    for (int l = 0; l < L_; ++l) s += xp[(size_t)l << 9];
    m[idx] = s * (1.0f / 1024.0f);
}

__global__ void colsub_kernel(float* __restrict__ x, const float* __restrict__ m)
{
    int idx = blockIdx.x * blockDim.x + threadIdx.x;  // over B*L*D
    int d = idx & 511;
    int b = idx >> 19;
    x[idx] -= m[(b << 9) + d];
}

// per-(b,c) mean over time of x_enc [B,1024,64]
__global__ void meanx_kernel(const float* __restrict__ x, float* __restrict__ m)
{
    int idx = blockIdx.x * blockDim.x + threadIdx.x;
    if (idx >= B_ * C_) return;
    int b = idx >> 6, c = idx & 63;
    const float* xp = x + (size_t)b * L_ * C_ + c;
    float s = 0.f;
    for (int l = 0; l < L_; ++l) s += xp[(size_t)l << 6];
    m[idx] = s * (1.0f / 1024.0f);
}

// build trend / seasonal_init decoder inputs
__global__ void builddec_kernel(const float* __restrict__ trenc, const float* __restrict__ seenc,
                                const float* __restrict__ meanc,
                                float* __restrict__ trend, float* __restrict__ seasin)
{
    int idx = blockIdx.x * blockDim.x + threadIdx.x;  // over B*1024*64
    int c = idx & 63;
    int l = (idx >> 6) & 1023;
    int b = idx >> 16;
    if (l < 512) {
        int src = (b << 16) + ((512 + l) << 6) + c;
        trend[idx] = trenc[src];
        seasin[idx] = seenc[src];
    } else {
        trend[idx] = meanc[(b << 6) + c];
        seasin[idx] = 0.f;
    }
}

__global__ void final_kernel(const float* __restrict__ trend, const float* __restrict__ s64,
                             float* __restrict__ out)
{
    int idx = blockIdx.x * blockDim.x + threadIdx.x;  // over B*512*64
    int c = idx & 63;
    int l = (idx >> 6) & 511;
    int b = idx >> 15;
    int src = (b << 16) + ((512 + l) << 6) + c;
    out[idx] = trend[src] + s64[src];
}

__global__ void zero_kernel(float* __restrict__ p, int n)
{
    int idx = blockIdx.x * blockDim.x + threadIdx.x;
    if (idx < n) p[idx] = 0.f;
}

// ---------------------------------------------------------------------------
extern "C" void kernel_launch(void* const* d_in, const int* in_sizes, int n_in,
                              void* d_out, int out_size, void* d_ws, size_t ws_size,
                              hipStream_t stream)
{
    auto F = [&](int i) { return (const float*)d_in[i]; };
    const float* x_enc     = F(0);
    const float* enc_emb_w = F(2);
    const float* dec_emb_w = F(3);
    const float* enc_Wq = F(4);  const float* enc_bq = F(5);
    const float* dsa_Wq = F(6);  const float* dsa_bq = F(7);
    const float* dca_Wq = F(8);  const float* dca_bq = F(9);
    const float* enc_Wk = F(10); const float* enc_bk = F(11);
    const float* dsa_Wk = F(12); const float* dsa_bk = F(13);
    const float* dca_Wk = F(14); const float* dca_bk = F(15);
    const float* enc_Wv = F(16); const float* enc_bv = F(17);
    const float* dsa_Wv = F(18); const float* dsa_bv = F(19);
    const float* dca_Wv = F(20); const float* dca_bv = F(21);
    const float* enc_Wo = F(22); const float* enc_bo = F(23);
    const float* dsa_Wo = F(24); const float* dsa_bo = F(25);
    const float* dca_Wo = F(26); const float* dca_bo = F(27);
    const float* enc_ff1 = F(28); const float* enc_ff2 = F(29);
    const float* enc_ng = F(30);  const float* enc_nb = F(31);
    const float* dec_ff1 = F(32); const float* dec_ff2 = F(33);
    const float* dec_trend_w = F(34);
    const float* proj_w = F(35);  const float* proj_b = F(36);

    constexpr size_t F512 = (size_t)B_ * L_ * D_;   // 8388608
    constexpr size_t F64  = (size_t)B_ * L_ * C_;   // 1048576
    size_t need = (7 * F512 + 5 * F64 + 1024 + 16384 + 320 + 320 + 8192) * 4;
    if (ws_size < need) return;

    float* ws = (float*)d_ws;
    float* X      = ws;
    float* T1     = ws + F512;
    float* T2     = ws + 2 * F512;
    float* T3     = ws + 3 * F512;
    float* T4     = ws + 4 * F512;
    float* ENCOUT = ws + 5 * F512;
    float* TSUM   = ws + 6 * F512;
    float* SB     = ws + 7 * F512;
    float* TREND  = SB;
    float* SEASIN = SB + F64;
    float* S64    = SB + 2 * F64;
    float* SEENC  = SB + 3 * F64;
    float* TRENC  = SB + 4 * F64;
    float* MEANC  = SB + 5 * F64;
    float* G      = MEANC + 1024;
    float* TCW    = G + 16384;
    int*   DEL    = (int*)(TCW + 320);
    float* LNMEAN = (float*)(DEL + 320);
    float* OUT    = (float*)d_out;

    const int M = B_ * L_;  // 16384

    auto gemm = [&](const float* A, const float* Bm, float* Cm, const float* bias,
                    int Mm, int Nn, int Kk, int flags, int shift = 0, int shiftL = 0) {
        dim3 g(Nn / GBN, Mm / GBM);
        gemm_f32<<<g, 256, 0, stream>>>(A, Bm, Cm, bias, Mm, Nn, Kk, flags, shift, shiftL);
    };
    auto attention = [&](const float* qin, const float* kvin,
                         const float* Wq, const float* bq, const float* Wk, const float* bk,
                         const float* Wv, const float* bv, const float* Wo, const float* bo,
                         float* qb, float* kb, float* vb, float* ab, float* xout) {
        gemm(qin,  Wq, qb, bq, M, D_, D_, 0);
        gemm(kvin, Wk, kb, bk, M, D_, D_, 0);
        gemm(kvin, Wv, vb, bv, M, D_, D_, 0);
        zero_kernel<<<16384 / 256, 256, 0, stream>>>(G, 16384);
        corr_diag<<<dim3(16, 16, 16), 256, 0, stream>>>(qb, kb, G);
        topk_kernel<<<16, 256, 0, stream>>>(G, DEL, TCW);
        agg_kernel<<<(int)(F512 / 256), 256, 0, stream>>>(vb, DEL, TCW, ab);
        gemm(ab, Wo, xout, bo, M, D_, D_, 1);  // residual accumulate
    };
    auto ffblock = [&](float* xbuf, const float* W1, const float* W2) {
        for (int c = 0; c < 4; ++c) {
            gemm(xbuf + (size_t)c * 4096 * D_, W1, T4, nullptr, 4096, DFF_, D_, 2);
            gemm(T4, W2, xbuf + (size_t)c * 4096 * D_, nullptr, 4096, D_, DFF_, 1);
        }
    };

    // ---------------- prep: decomposition of x_enc, decoder inits -----------
    decomp_kernel<<<(B_ * C_ * 8 + 255) / 256, 256, 0, stream>>>(x_enc, SEENC, TRENC, B_, L_, C_, 8, 1);
    meanx_kernel<<<(B_ * C_ + 255) / 256, 256, 0, stream>>>(x_enc, MEANC);
    builddec_kernel<<<(int)(F64 / 256), 256, 0, stream>>>(TRENC, SEENC, MEANC, TREND, SEASIN);

    // ---------------- encoder ----------------------------------------------
    gemm(x_enc, enc_emb_w,                X, nullptr, M, D_, C_, 0, -1, L_);
    gemm(x_enc, enc_emb_w + 1 * C_ * D_,  X, nullptr, M, D_, C_, 1,  0, L_);
    gemm(x_enc, enc_emb_w + 2 * C_ * D_,  X, nullptr, M, D_, C_, 1,  1, L_);
    addpos_kernel<<<(int)(F512 / 256), 256, 0, stream>>>(X);

    for (int l = 0; l < 2; ++l) {
        const float* Wq = enc_Wq + (size_t)l * D_ * D_; const float* bq = enc_bq + l * D_;
        const float* Wk = enc_Wk + (size_t)l * D_ * D_; const float* bk = enc_bk + l * D_;
        const float* Wv = enc_Wv + (size_t)l * D_ * D_; const float* bv = enc_bv + l * D_;
        const float* Wo = enc_Wo + (size_t)l * D_ * D_; const float* bo = enc_bo + l * D_;
        attention(X, X, Wq, bq, Wk, bk, Wv, bv, Wo, bo, T1, T2, T3, T4, X);
        decomp_kernel<<<(B_ * D_ * 8 + 255) / 256, 256, 0, stream>>>(X, T1, nullptr, B_, L_, D_, 8, 0);
        ffblock(T1, enc_ff1 + (size_t)l * D_ * DFF_, enc_ff2 + (size_t)l * DFF_ * D_);
        decomp_kernel<<<(B_ * D_ * 8 + 255) / 256, 256, 0, stream>>>(T1, X, nullptr, B_, L_, D_, 8, 0);
    }
    lnrow_kernel<<<M, 256, 0, stream>>>(X, enc_ng, enc_nb, ENCOUT);
    colmean_kernel<<<(B_ * D_ + 255) / 256, 256, 0, stream>>>(ENCOUT, LNMEAN);
    colsub_kernel<<<(int)(F512 / 256), 256, 0, stream>>>(ENCOUT, LNMEAN);

    // ---------------- decoder ----------------------------------------------
    float* XD = X;  // encoder activation buffer is free now
    gemm(SEASIN, dec_emb_w,               XD, nullptr, M, D_, C_, 0, -1, L_);
    gemm(SEASIN, dec_emb_w + 1 * C_ * D_, XD, nullptr, M, D_, C_, 1,  0, L_);
    gemm(SEASIN, dec_emb_w + 2 * C_ * D_, XD, nullptr, M, D_, C_, 1,  1, L_);
    addpos_kernel<<<(int)(F512 / 256), 256, 0, stream>>>(XD);

    // self attention + decomp (t1 -> TSUM, write)
    attention(XD, XD, dsa_Wq, dsa_bq, dsa_Wk, dsa_bk, dsa_Wv, dsa_bv, dsa_Wo, dsa_bo,
              T1, T2, T3, T4, XD);
    decomp_kernel<<<(B_ * D_ * 8 + 255) / 256, 256, 0, stream>>>(XD, T1, TSUM, B_, L_, D_, 8, 1);

    // cross attention (q from T1, kv from ENCOUT) + decomp (t2 -> TSUM, add)
    gemm(T1,     dca_Wq, T2, dca_bq, M, D_, D_, 0);
    gemm(ENCOUT, dca_Wk, T3, dca_bk, M, D_, D_, 0);
    gemm(ENCOUT, dca_Wv, T4, dca_bv, M, D_, D_, 0);
    zero_kernel<<<16384 / 256, 256, 0, stream>>>(G, 16384);
    corr_diag<<<dim3(16, 16, 16), 256, 0, stream>>>(T2, T3, G);
    topk_kernel<<<16, 256, 0, stream>>>(G, DEL, TCW);
    agg_kernel<<<(int)(F512 / 256), 256, 0, stream>>>(T4, DEL, TCW, XD);
    gemm(XD, dca_Wo, T1, dca_bo, M, D_, D_, 1);
    decomp_kernel<<<(B_ * D_ * 8 + 255) / 256, 256, 0, stream>>>(T1, XD, TSUM, B_, L_, D_, 8, 2);

    // feed-forward + decomp (t3 -> TSUM, add)
    ffblock(XD, dec_ff1, dec_ff2);
    decomp_kernel<<<(B_ * D_ * 8 + 255) / 256, 256, 0, stream>>>(XD, T1, TSUM, B_, L_, D_, 8, 2);

    // trend projection conv (3 taps) accumulated onto TREND
    gemm(TSUM, dec_trend_w,               TREND, nullptr, M, C_, D_, 1, -1, L_);
    gemm(TSUM, dec_trend_w + 1 * D_ * C_, TREND, nullptr, M, C_, D_, 1,  0, L_);
    gemm(TSUM, dec_trend_w + 2 * D_ * C_, TREND, nullptr, M, C_, D_, 1,  1, L_);

    // seasonal projection + final output
    gemm(T1, proj_w, S64, proj_b, M, C_, D_, 0);
    final_kernel<<<(B_ * 512 * C_) / 256, 256, 0, stream>>>(TREND, S64, OUT);
}

// Round 2
// 4949.246 us; speedup vs baseline: 1.8358x; 1.8358x over previous
//
#include <hip/hip_runtime.h>
#include <math.h>

#define B_   16
#define L_   1024
#define C_   64
#define D_   512
#define DFF_ 2048
#define TOPK_ 20

constexpr int GBM = 64, GBN = 64, GBK = 16;

typedef float f4 __attribute__((ext_vector_type(4)));
typedef float f32x4 __attribute__((ext_vector_type(4)));
typedef short bf16x8 __attribute__((ext_vector_type(8)));
typedef unsigned short u16x8 __attribute__((ext_vector_type(8)));

__device__ __forceinline__ unsigned short f2bf(float f) {
    union { float f; unsigned u; } a; a.f = f;
    unsigned r = a.u + 0x7fff + ((a.u >> 16) & 1);
    return (unsigned short)(r >> 16);
}
__device__ __forceinline__ float bf2f(unsigned short h) {
    union { unsigned u; float f; } a; a.u = ((unsigned)h) << 16;
    return a.f;
}

__device__ __forceinline__ void gld16(const void* g, void* l) {
    __builtin_amdgcn_global_load_lds(
        (const __attribute__((address_space(1))) unsigned int*)g,
        (__attribute__((address_space(3))) unsigned int*)l, 16, 0, 0);
}

// ---------------------------------------------------------------------------
// bf16 MFMA GEMM: C[M,N] = op(A[M,K] @ B[K,N] + bias)
// A: bf16 [M][K] row-major. Bt: bf16 [N][K] (pre-transposed weight).
// Cf: f32 out (flags&1: accumulate). Cb: bf16 out. flags&2: exact GELU.
// Tile 128x128, BK=32, 256 threads = 4 waves (2x2), each wave 64x64 via
// 4x4 fragments of mfma_f32_16x16x32_bf16. global_load_lds width-16 staging.
// ---------------------------------------------------------------------------
__global__ __launch_bounds__(256)
void gemm_bf16(const unsigned short* __restrict__ A, const unsigned short* __restrict__ Bt,
               float* __restrict__ Cf, unsigned short* __restrict__ Cb,
               const float* __restrict__ bias, int M, int N, int K, int flags)
{
    __shared__ unsigned short As[128 * 32];
    __shared__ unsigned short Bs[128 * 32];
    const int tid = threadIdx.x;
    const int wave = tid >> 6, lane = tid & 63;
    const int bm = blockIdx.y * 128, bn = blockIdx.x * 128;
    const int wm = (wave >> 1) << 6, wn = (wave & 1) << 6;

    // staging: wave w covers rows w*32..w*32+31 (2 instr x 16 rows each)
    const int r0 = (wave << 5) + (lane >> 2);     // first 16-row chunk row
    const int kq = (lane & 3) << 3;               // k sub-offset (8 bf16 = 16B)
    const unsigned short* Ap0 = A + (size_t)(bm + r0) * K + kq;
    const unsigned short* Ap1 = Ap0 + (size_t)16 * K;
    const unsigned short* Bp0 = Bt + (size_t)(bn + r0) * K + kq;
    const unsigned short* Bp1 = Bp0 + (size_t)16 * K;
    unsigned short* Al0 = &As[(wave << 5) * 32];
    unsigned short* Al1 = &As[((wave << 5) + 16) * 32];
    unsigned short* Bl0 = &Bs[(wave << 5) * 32];
    unsigned short* Bl1 = &Bs[((wave << 5) + 16) * 32];

    const int la = lane & 15, hi = lane >> 4;
    f32x4 acc[4][4] = {};

    for (int k0 = 0; k0 < K; k0 += 32) {
        gld16(Ap0 + k0, Al0);
        gld16(Ap1 + k0, Al1);
        gld16(Bp0 + k0, Bl0);
        gld16(Bp1 + k0, Bl1);
        __syncthreads();
        bf16x8 a[4], b[4];
#pragma unroll
        for (int i = 0; i < 4; ++i) {
            a[i] = *(const bf16x8*)&As[(wm + i * 16 + la) * 32 + hi * 8];
            b[i] = *(const bf16x8*)&Bs[(wn + i * 16 + la) * 32 + hi * 8];
        }
#pragma unroll
        for (int mi = 0; mi < 4; ++mi)
#pragma unroll
            for (int ni = 0; ni < 4; ++ni)
                acc[mi][ni] = __builtin_amdgcn_mfma_f32_16x16x32_bf16(a[mi], b[ni], acc[mi][ni], 0, 0, 0);
        __syncthreads();
    }

#pragma unroll
    for (int mi = 0; mi < 4; ++mi) {
#pragma unroll
        for (int r = 0; r < 4; ++r) {
            int m = bm + wm + mi * 16 + hi * 4 + r;
#pragma unroll
            for (int ni = 0; ni < 4; ++ni) {
                int n = bn + wn + ni * 16 + la;
                float c = acc[mi][ni][r];
                if (bias) c += bias[n];
                if (flags & 2) c = 0.5f * c * (1.0f + erff(c * 0.70710678118654752f));
                size_t o = (size_t)m * N + n;
                if (Cf) { if (flags & 1) Cf[o] += c; else Cf[o] = c; }
                if (Cb) Cb[o] = f2bf(c);
            }
        }
    }
}

// transpose + cast: W [R][Cc] f32 -> Wt [Cc][R] bf16
__global__ __launch_bounds__(256)
void tcast_kernel(const float* __restrict__ W, unsigned short* __restrict__ Wt, int R, int Cc)
{
    __shared__ float t[32][33];
    int bx = blockIdx.x * 32, by = blockIdx.y * 32;
    int tx = threadIdx.x & 31, ty = threadIdx.x >> 5;
#pragma unroll
    for (int i = 0; i < 32; i += 8)
        t[ty + i][tx] = W[(size_t)(by + ty + i) * Cc + bx + tx];
    __syncthreads();
#pragma unroll
    for (int i = 0; i < 32; i += 8)
        Wt[(size_t)(bx + ty + i) * R + by + tx] = f2bf(t[tx][ty + i]);
}

// ---------------------------------------------------------------------------
// Generic f32 GEMM (kept for embeddings / trend conv / proj).
// flags bit0: accumulate, bit1: GELU. shiftL>0: circular A-row remap.
// ---------------------------------------------------------------------------
__global__ __launch_bounds__(256)
void gemm_f32(const float* __restrict__ A, const float* __restrict__ Bm,
              float* __restrict__ Cm, const float* __restrict__ bias,
              int M, int N, int K, int flags, int shift, int shiftL)
{
    __shared__ float As[GBK][GBM + 4];
    __shared__ float Bs[GBK][GBN + 4];
    const int tid = threadIdx.x;
    const int bm = blockIdx.y * GBM;
    const int bn = blockIdx.x * GBN;
    const int tx = tid & 15, ty = tid >> 4;
    const int a_k = tid & 15, a_m0 = tid >> 4;
    const int b_n = tid & 63, b_k0 = tid >> 6;
    float acc[4][4] = {};
    for (int k0 = 0; k0 < K; k0 += GBK) {
#pragma unroll
        for (int r = 0; r < 4; ++r) {
            int m = bm + a_m0 + r * 16;
            int row = m;
            if (shiftL > 0) {
                int l = m & (shiftL - 1);
                int base = m - l;
                l += shift;
                if (l < 0) l += shiftL; else if (l >= shiftL) l -= shiftL;
                row = base + l;
            }
            As[a_k][a_m0 + r * 16] = A[(size_t)row * K + (k0 + a_k)];
        }
#pragma unroll
        for (int r = 0; r < 4; ++r) {
            int kk = b_k0 + r * 4;
            Bs[kk][b_n] = Bm[(size_t)(k0 + kk) * N + (bn + b_n)];
        }
        __syncthreads();
#pragma unroll
        for (int kk = 0; kk < GBK; ++kk) {
            f4 av = *(const f4*)&As[kk][ty * 4];
            f4 bv = *(const f4*)&Bs[kk][tx * 4];
#pragma unroll
            for (int i = 0; i < 4; ++i)
#pragma unroll
                for (int j = 0; j < 4; ++j)
                    acc[i][j] = fmaf(av[i], bv[j], acc[i][j]);
        }
        __syncthreads();
    }
#pragma unroll
    for (int i = 0; i < 4; ++i) {
        int m = bm + ty * 4 + i;
#pragma unroll
        for (int j = 0; j < 4; ++j) {
            int n = bn + tx * 4 + j;
            float c = acc[i][j];
            if (bias) c += bias[n];
            if (flags & 2) c = 0.5f * c * (1.0f + erff(c * 0.70710678118654752f));
            size_t o = (size_t)m * N + n;
            if (flags & 1) Cm[o] += c; else Cm[o] = c;
        }
    }
}

// ---------------------------------------------------------------------------
// Autocorrelation scores (f32, unchanged): G[b,n] += diag sums of Q*K^T tile
// ---------------------------------------------------------------------------
__global__ __launch_bounds__(256)
void corr_diag(const float* __restrict__ Q, const float* __restrict__ Km,
               float* __restrict__ G)
{
    __shared__ float Qs[GBK][GBM + 4];
    __shared__ float Ks[GBK][GBN + 4];
    __shared__ float diag[128];
    const int tid = threadIdx.x;
    const int b = blockIdx.z;
    const int bt = blockIdx.y * GBM;
    const int bs = blockIdx.x * GBN;
    const float* Qb = Q + ((size_t)b << 19);
    const float* Kb = Km + ((size_t)b << 19);
    const int tx = tid & 15, ty = tid >> 4;
    const int a_k = tid & 15, a_m0 = tid >> 4;
    float acc[4][4] = {};
    for (int k0 = 0; k0 < 512; k0 += GBK) {
#pragma unroll
        for (int r = 0; r < 4; ++r)
            Qs[a_k][a_m0 + r * 16] = Qb[(size_t)(bt + a_m0 + r * 16) * 512 + k0 + a_k];
#pragma unroll
        for (int r = 0; r < 4; ++r)
            Ks[a_k][a_m0 + r * 16] = Kb[(size_t)(bs + a_m0 + r * 16) * 512 + k0 + a_k];
        __syncthreads();
#pragma unroll
        for (int kk = 0; kk < GBK; ++kk) {
            f4 av = *(const f4*)&Qs[kk][ty * 4];
            f4 bv = *(const f4*)&Ks[kk][tx * 4];
#pragma unroll
            for (int i = 0; i < 4; ++i)
#pragma unroll
                for (int j = 0; j < 4; ++j)
                    acc[i][j] = fmaf(av[i], bv[j], acc[i][j]);
        }
        __syncthreads();
    }
    if (tid < 127) diag[tid] = 0.f;
    __syncthreads();
#pragma unroll
    for (int i = 0; i < 4; ++i)
#pragma unroll
        for (int j = 0; j < 4; ++j) {
            int li = (ty * 4 + i) - (tx * 4 + j) + 63;
            atomicAdd(&diag[li], acc[i][j]);
        }
    __syncthreads();
    if (tid < 127) {
        int n = (bt - bs + tid - 63) & 1023;
        atomicAdd(&G[(b << 10) + n], diag[tid]);
    }
}

__global__ __launch_bounds__(256)
void topk_kernel(const float* __restrict__ G, int* __restrict__ delay,
                 float* __restrict__ tc)
{
    __shared__ float vals[1024];
    __shared__ float pv[256];
    __shared__ int   pi[256];
    __shared__ float wsel[TOPK_];
    __shared__ int   isel[TOPK_];
    const int b = blockIdx.x, tid = threadIdx.x;
    for (int i = tid; i < 1024; i += 256) vals[i] = G[(b << 10) + i] * (1.0f / 512.0f);
    __syncthreads();
    for (int it = 0; it < TOPK_; ++it) {
        float bv = -INFINITY; int bi = 0;
        for (int i = tid * 4; i < tid * 4 + 4; ++i) {
            float v = vals[i];
            if (v > bv) { bv = v; bi = i; }
        }
        pv[tid] = bv; pi[tid] = bi;
        __syncthreads();
        if (tid == 0) {
            float m = pv[0]; int mi = pi[0];
            for (int t = 1; t < 256; ++t)
                if (pv[t] > m) { m = pv[t]; mi = pi[t]; }
            wsel[it] = m; isel[it] = mi;
            vals[mi] = -INFINITY;
        }
        __syncthreads();
    }
    if (tid == 0) {
        float m = wsel[0];
#pragma unroll
        for (int i = 1; i < TOPK_; ++i) m = fmaxf(m, wsel[i]);
        float e[TOPK_], s = 0.f;
#pragma unroll
        for (int i = 0; i < TOPK_; ++i) { e[i] = expf(wsel[i] - m); s += e[i]; }
        float inv = 1.0f / s;
#pragma unroll
        for (int i = 0; i < TOPK_; ++i) {
            tc[b * TOPK_ + i] = e[i] * inv;
            delay[b * TOPK_ + i] = isel[i];
        }
    }
}

// out[b,l,d] = sum_i tc[b,i] * V[b,(l+delay)%1024,d], bf16 in/out, 8-wide
__global__ void agg_kernel(const unsigned short* __restrict__ V, const int* __restrict__ delay,
                           const float* __restrict__ tc, unsigned short* __restrict__ out)
{
    int idx = (blockIdx.x * blockDim.x + threadIdx.x) * 8;
    int d = idx & 511;
    int l = (idx >> 9) & 1023;
    int b = idx >> 19;
    const unsigned short* Vb = V + ((size_t)b << 19);
    float s[8] = {};
#pragma unroll
    for (int i = 0; i < TOPK_; ++i) {
        int row = (l + delay[b * TOPK_ + i]) & 1023;
        float w = tc[b * TOPK_ + i];
        u16x8 v = *(const u16x8*)&Vb[((size_t)row << 9) + d];
#pragma unroll
        for (int j = 0; j < 8; ++j)
            s[j] = fmaf(w, bf2f(v[j]), s[j]);
    }
    u16x8 o;
#pragma unroll
    for (int j = 0; j < 8; ++j) o[j] = f2bf(s[j]);
    *(u16x8*)&out[idx] = o;
}

// ---------------------------------------------------------------------------
// series_decomp with optional bf16 dual-out of the seasonal part.
// tmode: 0 seasonal only, 1 write trend, 2 accumulate trend.
// ---------------------------------------------------------------------------
__global__ void decomp_kernel(const float* __restrict__ x, float* __restrict__ seas,
                              unsigned short* __restrict__ seasb,
                              float* __restrict__ trend, int Bn, int Ln, int Ch,
                              int nseg, int tmode)
{
    int idx = blockIdx.x * blockDim.x + threadIdx.x;
    int total = Bn * Ch * nseg;
    if (idx >= total) return;
    int ch = idx % Ch;
    int rest = idx / Ch;
    int seg = rest % nseg;
    int b = rest / nseg;
    int segL = Ln / nseg;
    int l0 = seg * segL;
    const float* xp = x + (size_t)b * Ln * Ch + ch;
    float* sp = seas + (size_t)b * Ln * Ch + ch;
    unsigned short* bp = seasb ? seasb + (size_t)b * Ln * Ch + ch : nullptr;
    float* tp = trend ? trend + (size_t)b * Ln * Ch + ch : nullptr;
    float s = 0.f;
    for (int j = -12; j <= 12; ++j) {
        int t = l0 + j;
        t = t < 0 ? 0 : (t > Ln - 1 ? Ln - 1 : t);
        s += xp[(size_t)t * Ch];
    }
    for (int l = l0; l < l0 + segL; ++l) {
        float mm = s * (1.0f / 25.0f);
        float v = xp[(size_t)l * Ch] - mm;
        sp[(size_t)l * Ch] = v;
        if (bp) bp[(size_t)l * Ch] = f2bf(v);
        if (tmode == 1) tp[(size_t)l * Ch] = mm;
        else if (tmode == 2) tp[(size_t)l * Ch] += mm;
        int ta = l + 13; if (ta > Ln - 1) ta = Ln - 1;
        int ts = l - 12; if (ts < 0) ts = 0;
        s += xp[(size_t)ta * Ch] - xp[(size_t)ts * Ch];
    }
}

// x += pos emb (f32 in place) and write bf16 copy
__global__ void addpos_kernel(float* __restrict__ x, unsigned short* __restrict__ xb)
{
    int idx = blockIdx.x * blockDim.x + threadIdx.x;
    int d = idx & 511;
    int l = (idx >> 9) & 1023;
    int i2 = d & ~1;
    float div = expf(-(float)i2 * 0.017988946039015984f);
    float ang = (float)l * div;
    float v = x[idx] + ((d & 1) ? cosf(ang) : sinf(ang));
    x[idx] = v;
    xb[idx] = f2bf(v);
}

__global__ __launch_bounds__(256)
void lnrow_kernel(const float* __restrict__ x, const float* __restrict__ g,
                  const float* __restrict__ bv, float* __restrict__ out)
{
    __shared__ float sh1[4], sh2[4];
    int row = blockIdx.x, tid = threadIdx.x;
    const float* xr = x + ((size_t)row << 9);
    float v0 = xr[tid], v1 = xr[tid + 256];
    float s = v0 + v1, q = v0 * v0 + v1 * v1;
#pragma unroll
    for (int o = 32; o > 0; o >>= 1) {
        s += __shfl_down(s, o, 64);
        q += __shfl_down(q, o, 64);
    }
    int wid = tid >> 6;
    if ((tid & 63) == 0) { sh1[wid] = s; sh2[wid] = q; }
    __syncthreads();
    if (tid == 0) {
        sh1[0] = sh1[0] + sh1[1] + sh1[2] + sh1[3];
        sh2[0] = sh2[0] + sh2[1] + sh2[2] + sh2[3];
    }
    __syncthreads();
    float mu = sh1[0] * (1.0f / 512.0f);
    float var = sh2[0] * (1.0f / 512.0f) - mu * mu;
    float inv = rsqrtf(var + 1e-5f);
    out[((size_t)row << 9) + tid] = (v0 - mu) * inv * g[tid] + bv[tid];
    out[((size_t)row << 9) + tid + 256] = (v1 - mu) * inv * g[tid + 256] + bv[tid + 256];
}

__global__ void colmean_kernel(const float* __restrict__ x, float* __restrict__ m)
{
    int idx = blockIdx.x * blockDim.x + threadIdx.x;
    if (idx >= B_ * D_) return;
    int b = idx >> 9, d = idx & 511;
    const float* xp = x + ((size_t)b << 19) + d;
    float s = 0.f;
    for (int l = 0; l < L_; ++l) s += xp[(size_t)l << 9];
    m[idx] = s * (1.0f / 1024.0f);
}

// out_bf16 = x - colmean (encoder output, bf16 only)
__global__ void colsub_kernel(const float* __restrict__ x, const float* __restrict__ m,
                              unsigned short* __restrict__ out)
{
    int idx = blockIdx.x * blockDim.x + threadIdx.x;
    int d = idx & 511;
    int b = idx >> 19;
    out[idx] = f2bf(x[idx] - m[(b << 9) + d]);
}

__global__ void meanx_kernel(const float* __restrict__ x, float* __restrict__ m)
{
    int idx = blockIdx.x * blockDim.x + threadIdx.x;
    if (idx >= B_ * C_) return;
    int b = idx >> 6, c = idx & 63;
    const float* xp = x + (size_t)b * L_ * C_ + c;
    float s = 0.f;
    for (int l = 0; l < L_; ++l) s += xp[(size_t)l << 6];
    m[idx] = s * (1.0f / 1024.0f);
}

__global__ void builddec_kernel(const float* __restrict__ trenc, const float* __restrict__ seenc,
                                const float* __restrict__ meanc,
                                float* __restrict__ trend, float* __restrict__ seasin)
{
    int idx = blockIdx.x * blockDim.x + threadIdx.x;
    int c = idx & 63;
    int l = (idx >> 6) & 1023;
    int b = idx >> 16;
    if (l < 512) {
        int src = (b << 16) + ((512 + l) << 6) + c;
        trend[idx] = trenc[src];
        seasin[idx] = seenc[src];
    } else {
        trend[idx] = meanc[(b << 6) + c];
        seasin[idx] = 0.f;
    }
}

__global__ void final_kernel(const float* __restrict__ trend, const float* __restrict__ s64,
                             float* __restrict__ out)
{
    int idx = blockIdx.x * blockDim.x + threadIdx.x;
    int c = idx & 63;
    int l = (idx >> 6) & 511;
    int b = idx >> 15;
    int src = (b << 16) + ((512 + l) << 6) + c;
    out[idx] = trend[src] + s64[src];
}

__global__ void zero_kernel(float* __restrict__ p, int n)
{
    int idx = blockIdx.x * blockDim.x + threadIdx.x;
    if (idx < n) p[idx] = 0.f;
}

// ---------------------------------------------------------------------------
extern "C" void kernel_launch(void* const* d_in, const int* in_sizes, int n_in,
                              void* d_out, int out_size, void* d_ws, size_t ws_size,
                              hipStream_t stream)
{
    auto F = [&](int i) { return (const float*)d_in[i]; };
    const float* x_enc     = F(0);
    const float* enc_emb_w = F(2);
    const float* dec_emb_w = F(3);
    const float* enc_Wq = F(4);  const float* enc_bq = F(5);
    const float* dsa_Wq = F(6);  const float* dsa_bq = F(7);
    const float* dca_Wq = F(8);  const float* dca_bq = F(9);
    const float* enc_Wk = F(10); const float* enc_bk = F(11);
    const float* dsa_Wk = F(12); const float* dsa_bk = F(13);
    const float* dca_Wk = F(14); const float* dca_bk = F(15);
    const float* enc_Wv = F(16); const float* enc_bv = F(17);
    const float* dsa_Wv = F(18); const float* dsa_bv = F(19);
    const float* dca_Wv = F(20); const float* dca_bv = F(21);
    const float* enc_Wo = F(22); const float* enc_bo = F(23);
    const float* dsa_Wo = F(24); const float* dsa_bo = F(25);
    const float* dca_Wo = F(26); const float* dca_bo = F(27);
    const float* enc_ff1 = F(28); const float* enc_ff2 = F(29);
    const float* enc_ng = F(30);  const float* enc_nb = F(31);
    const float* dec_ff1 = F(32); const float* dec_ff2 = F(33);
    const float* dec_trend_w = F(34);
    const float* proj_w = F(35);  const float* proj_b = F(36);

    constexpr size_t F512 = (size_t)B_ * L_ * D_;   // 8388608
    constexpr size_t F64  = (size_t)B_ * L_ * C_;   // 1048576
    constexpr size_t SMALL = 1024 + 16384 + 320 + 320 + 8192;
    constexpr size_t WTSN = 2 * 1024 * 1024;        // bf16 weight scratch elems
    size_t need = (5 * F512 + 2 * F64 + SMALL) * 4 + (4 * F512 + WTSN) * 2;
    if (ws_size < need) return;

    float* X      = (float*)d_ws;
    float* T1     = X + F512;
    float* T2     = T1 + F512;
    float* T3     = T2 + F512;
    float* TSUM   = T3 + F512;
    float* SEASIN = TSUM + F512;
    float* TREND  = SEASIN + F64;
    float* MEANC  = TREND + F64;
    float* G      = MEANC + 1024;
    float* TCW    = G + 16384;
    int*   DEL    = (int*)(TCW + 320);
    float* LNMEAN = (float*)(DEL + 320);
    unsigned short* AB  = (unsigned short*)(LNMEAN + 8192);
    unsigned short* EB  = AB + F512;
    unsigned short* VB  = EB + F512;
    unsigned short* HB  = VB + F512;
    unsigned short* WTS = HB + F512;
    float* OUT = (float*)d_out;

    const int M = B_ * L_;  // 16384

    auto gemm = [&](const float* A, const float* Bm, float* Cm, const float* bias,
                    int Mm, int Nn, int Kk, int flags, int shift = 0, int shiftL = 0) {
        dim3 g(Nn / GBN, Mm / GBM);
        gemm_f32<<<g, 256, 0, stream>>>(A, Bm, Cm, bias, Mm, Nn, Kk, flags, shift, shiftL);
    };
    auto mgemm = [&](const unsigned short* A, const unsigned short* Bt, float* Cf,
                     unsigned short* Cb, const float* bias, int Mm, int Nn, int Kk, int flags) {
        dim3 g(Nn / 128, Mm / 128);
        gemm_bf16<<<g, 256, 0, stream>>>(A, Bt, Cf, Cb, bias, Mm, Nn, Kk, flags);
    };
    auto tcast = [&](const float* W, unsigned short* Wt, int R, int Cc) {
        tcast_kernel<<<dim3(Cc / 32, R / 32), 256, 0, stream>>>(W, Wt, R, Cc);
    };
    auto attn = [&](const unsigned short* qin, const unsigned short* kvin,
                    const float* Wq, const float* bq, const float* Wk, const float* bk,
                    const float* Wv, const float* bvp, const float* Wo, const float* bo,
                    float* resid) {
        unsigned short* Wt0 = WTS;
        unsigned short* Wt1 = WTS + 262144;
        unsigned short* Wt2 = WTS + 524288;
        unsigned short* Wt3 = WTS + 786432;
        tcast(Wq, Wt0, 512, 512);
        tcast(Wk, Wt1, 512, 512);
        tcast(Wv, Wt2, 512, 512);
        tcast(Wo, Wt3, 512, 512);
        mgemm(qin,  Wt0, T2, nullptr, bq, M, 512, 512, 0);
        mgemm(kvin, Wt1, T3, nullptr, bk, M, 512, 512, 0);
        mgemm(kvin, Wt2, nullptr, VB, bvp, M, 512, 512, 0);
        zero_kernel<<<16384 / 256, 256, 0, stream>>>(G, 16384);
        corr_diag<<<dim3(16, 16, 16), 256, 0, stream>>>(T2, T3, G);
        topk_kernel<<<16, 256, 0, stream>>>(G, DEL, TCW);
        agg_kernel<<<(int)(F512 / 8 / 256), 256, 0, stream>>>(VB, DEL, TCW, HB);
        mgemm(HB, Wt3, resid, nullptr, bo, M, 512, 512, 1);
    };
    auto ffblock = [&](const unsigned short* xin, const float* W1, const float* W2, float* resid) {
        unsigned short* Wf1 = WTS;
        unsigned short* Wf2 = WTS + 1048576;
        tcast(W1, Wf1, 512, 2048);
        tcast(W2, Wf2, 2048, 512);
        for (int c = 0; c < 4; ++c) {
            mgemm(xin + (size_t)c * 4096 * 512, Wf1, nullptr, HB, nullptr, 4096, 2048, 512, 2);
            mgemm(HB, Wf2, resid + (size_t)c * 4096 * 512, nullptr, nullptr, 4096, 512, 2048, 1);
        }
    };

    // ---------------- prep: decomposition of x_enc, decoder inits -----------
    float* SEENC = T2;  // aliases: prep phase only
    float* TRENC = T3;
    decomp_kernel<<<(B_ * C_ * 8 + 255) / 256, 256, 0, stream>>>(x_enc, SEENC, nullptr, TRENC, B_, L_, C_, 8, 1);
    meanx_kernel<<<(B_ * C_ + 255) / 256, 256, 0, stream>>>(x_enc, MEANC);
    builddec_kernel<<<(int)(F64 / 256), 256, 0, stream>>>(TRENC, SEENC, MEANC, TREND, SEASIN);

    // ---------------- encoder ----------------------------------------------
    gemm(x_enc, enc_emb_w,               X, nullptr, M, D_, C_, 0, -1, L_);
    gemm(x_enc, enc_emb_w + 1 * C_ * D_, X, nullptr, M, D_, C_, 1,  0, L_);
    gemm(x_enc, enc_emb_w + 2 * C_ * D_, X, nullptr, M, D_, C_, 1,  1, L_);
    addpos_kernel<<<(int)(F512 / 256), 256, 0, stream>>>(X, AB);

    for (int l = 0; l < 2; ++l) {
        attn(AB, AB,
             enc_Wq + (size_t)l * D_ * D_, enc_bq + l * D_,
             enc_Wk + (size_t)l * D_ * D_, enc_bk + l * D_,
             enc_Wv + (size_t)l * D_ * D_, enc_bv + l * D_,
             enc_Wo + (size_t)l * D_ * D_, enc_bo + l * D_, X);
        decomp_kernel<<<(B_ * D_ * 8 + 255) / 256, 256, 0, stream>>>(X, T1, AB, nullptr, B_, L_, D_, 8, 0);
        ffblock(AB, enc_ff1 + (size_t)l * D_ * DFF_, enc_ff2 + (size_t)l * DFF_ * D_, T1);
        decomp_kernel<<<(B_ * D_ * 8 + 255) / 256, 256, 0, stream>>>(T1, X, AB, nullptr, B_, L_, D_, 8, 0);
    }
    lnrow_kernel<<<M, 256, 0, stream>>>(X, enc_ng, enc_nb, T1);
    colmean_kernel<<<(B_ * D_ + 255) / 256, 256, 0, stream>>>(T1, LNMEAN);
    colsub_kernel<<<(int)(F512 / 256), 256, 0, stream>>>(T1, LNMEAN, EB);

    // ---------------- decoder ----------------------------------------------
    float* XD = X;
    gemm(SEASIN, dec_emb_w,               XD, nullptr, M, D_, C_, 0, -1, L_);
    gemm(SEASIN, dec_emb_w + 1 * C_ * D_, XD, nullptr, M, D_, C_, 1,  0, L_);
    gemm(SEASIN, dec_emb_w + 2 * C_ * D_, XD, nullptr, M, D_, C_, 1,  1, L_);
    addpos_kernel<<<(int)(F512 / 256), 256, 0, stream>>>(XD, AB);

    attn(AB, AB, dsa_Wq, dsa_bq, dsa_Wk, dsa_bk, dsa_Wv, dsa_bv, dsa_Wo, dsa_bo, XD);
    decomp_kernel<<<(B_ * D_ * 8 + 255) / 256, 256, 0, stream>>>(XD, T1, AB, TSUM, B_, L_, D_, 8, 1);

    attn(AB, EB, dca_Wq, dca_bq, dca_Wk, dca_bk, dca_Wv, dca_bv, dca_Wo, dca_bo, T1);
    decomp_kernel<<<(B_ * D_ * 8 + 255) / 256, 256, 0, stream>>>(T1, XD, AB, TSUM, B_, L_, D_, 8, 2);

    ffblock(AB, dec_ff1, dec_ff2, XD);
    decomp_kernel<<<(B_ * D_ * 8 + 255) / 256, 256, 0, stream>>>(XD, T1, nullptr, TSUM, B_, L_, D_, 8, 2);

    // trend projection conv (3 taps) accumulated onto TREND
    gemm(TSUM, dec_trend_w,               TREND, nullptr, M, C_, D_, 1, -1, L_);
    gemm(TSUM, dec_trend_w + 1 * D_ * C_, TREND, nullptr, M, C_, D_, 1,  0, L_);
    gemm(TSUM, dec_trend_w + 2 * D_ * C_, TREND, nullptr, M, C_, D_, 1,  1, L_);

    // seasonal projection + final output
    float* S64 = T2;  // T2 free by now
    gemm(T1, proj_w, S64, proj_b, M, C_, D_, 0);
    final_kernel<<<(B_ * 512 * C_) / 256, 256, 0, stream>>>(TREND, S64, OUT);
}

// Round 3
// 4642.781 us; speedup vs baseline: 1.9570x; 1.0660x over previous
//
#include <hip/hip_runtime.h>
#include <math.h>

#define B_   16
#define L_   1024
#define C_   64
#define D_   512
#define DFF_ 2048
#define TOPK_ 20

constexpr int GBM = 64, GBN = 64, GBK = 16;
constexpr int CBM = 128, CBK = 32;

typedef float f4 __attribute__((ext_vector_type(4)));
typedef float f32x4 __attribute__((ext_vector_type(4)));
typedef short bf16x8 __attribute__((ext_vector_type(8)));
typedef unsigned short u16x8 __attribute__((ext_vector_type(8)));

__device__ __forceinline__ unsigned short f2bf(float f) {
    union { float f; unsigned u; } a; a.f = f;
    unsigned r = a.u + 0x7fff + ((a.u >> 16) & 1);
    return (unsigned short)(r >> 16);
}
__device__ __forceinline__ float bf2f(unsigned short h) {
    union { unsigned u; float f; } a; a.u = ((unsigned)h) << 16;
    return a.f;
}

__device__ __forceinline__ void gld16(const void* g, void* l) {
    __builtin_amdgcn_global_load_lds(
        (const __attribute__((address_space(1))) unsigned int*)g,
        (__attribute__((address_space(3))) unsigned int*)l, 16, 0, 0);
}

// ---------------------------------------------------------------------------
// bf16 MFMA GEMM: C[M,N] = op(A[M,K] @ B[K,N] + bias)
// A: bf16 [M][K] row-major. Bt: bf16 [N][K] (pre-transposed weight).
// Cf: f32 out (flags&1: accumulate). Cb: bf16 out. flags&2: exact GELU.
// Tile 128x128, BK=32, 256 threads = 4 waves (2x2), each wave 64x64 via
// 4x4 fragments of mfma_f32_16x16x32_bf16. global_load_lds width-16 staging.
// ---------------------------------------------------------------------------
__global__ __launch_bounds__(256)
void gemm_bf16(const unsigned short* __restrict__ A, const unsigned short* __restrict__ Bt,
               float* __restrict__ Cf, unsigned short* __restrict__ Cb,
               const float* __restrict__ bias, int M, int N, int K, int flags)
{
    __shared__ unsigned short As[128 * 32];
    __shared__ unsigned short Bs[128 * 32];
    const int tid = threadIdx.x;
    const int wave = tid >> 6, lane = tid & 63;
    const int bm = blockIdx.y * 128, bn = blockIdx.x * 128;
    const int wm = (wave >> 1) << 6, wn = (wave & 1) << 6;

    const int r0 = (wave << 5) + (lane >> 2);
    const int kq = (lane & 3) << 3;
    const unsigned short* Ap0 = A + (size_t)(bm + r0) * K + kq;
    const unsigned short* Ap1 = Ap0 + (size_t)16 * K;
    const unsigned short* Bp0 = Bt + (size_t)(bn + r0) * K + kq;
    const unsigned short* Bp1 = Bp0 + (size_t)16 * K;
    unsigned short* Al0 = &As[(wave << 5) * 32];
    unsigned short* Al1 = &As[((wave << 5) + 16) * 32];
    unsigned short* Bl0 = &Bs[(wave << 5) * 32];
    unsigned short* Bl1 = &Bs[((wave << 5) + 16) * 32];

    const int la = lane & 15, hi = lane >> 4;
    f32x4 acc[4][4] = {};

    for (int k0 = 0; k0 < K; k0 += 32) {
        gld16(Ap0 + k0, Al0);
        gld16(Ap1 + k0, Al1);
        gld16(Bp0 + k0, Bl0);
        gld16(Bp1 + k0, Bl1);
        __syncthreads();
        bf16x8 a[4], b[4];
#pragma unroll
        for (int i = 0; i < 4; ++i) {
            a[i] = *(const bf16x8*)&As[(wm + i * 16 + la) * 32 + hi * 8];
            b[i] = *(const bf16x8*)&Bs[(wn + i * 16 + la) * 32 + hi * 8];
        }
#pragma unroll
        for (int mi = 0; mi < 4; ++mi)
#pragma unroll
            for (int ni = 0; ni < 4; ++ni)
                acc[mi][ni] = __builtin_amdgcn_mfma_f32_16x16x32_bf16(a[mi], b[ni], acc[mi][ni], 0, 0, 0);
        __syncthreads();
    }

#pragma unroll
    for (int mi = 0; mi < 4; ++mi) {
#pragma unroll
        for (int r = 0; r < 4; ++r) {
            int m = bm + wm + mi * 16 + hi * 4 + r;
#pragma unroll
            for (int ni = 0; ni < 4; ++ni) {
                int n = bn + wn + ni * 16 + la;
                float c = acc[mi][ni][r];
                if (bias) c += bias[n];
                if (flags & 2) c = 0.5f * c * (1.0f + erff(c * 0.70710678118654752f));
                size_t o = (size_t)m * N + n;
                if (Cf) { if (flags & 1) Cf[o] += c; else Cf[o] = c; }
                if (Cb) Cb[o] = f2bf(c);
            }
        }
    }
}

// transpose + cast: W [R][Cc] f32 -> Wt [Cc][R] bf16
__global__ __launch_bounds__(256)
void tcast_kernel(const float* __restrict__ W, unsigned short* __restrict__ Wt, int R, int Cc)
{
    __shared__ float t[32][33];
    int bx = blockIdx.x * 32, by = blockIdx.y * 32;
    int tx = threadIdx.x & 31, ty = threadIdx.x >> 5;
#pragma unroll
    for (int i = 0; i < 32; i += 8)
        t[ty + i][tx] = W[(size_t)(by + ty + i) * Cc + bx + tx];
    __syncthreads();
#pragma unroll
    for (int i = 0; i < 32; i += 8)
        Wt[(size_t)(bx + ty + i) * R + by + tx] = f2bf(t[tx][ty + i]);
}

// ---------------------------------------------------------------------------
// Generic f32 GEMM (embeddings / trend conv / proj).
// flags bit0: accumulate, bit1: GELU. shiftL>0: circular A-row remap.
// ---------------------------------------------------------------------------
__global__ __launch_bounds__(256)
void gemm_f32(const float* __restrict__ A, const float* __restrict__ Bm,
              float* __restrict__ Cm, const float* __restrict__ bias,
              int M, int N, int K, int flags, int shift, int shiftL)
{
    __shared__ float As[GBK][GBM + 4];
    __shared__ float Bs[GBK][GBN + 4];
    const int tid = threadIdx.x;
    const int bm = blockIdx.y * GBM;
    const int bn = blockIdx.x * GBN;
    const int tx = tid & 15, ty = tid >> 4;
    const int a_k = tid & 15, a_m0 = tid >> 4;
    const int b_n = tid & 63, b_k0 = tid >> 6;
    float acc[4][4] = {};
    for (int k0 = 0; k0 < K; k0 += GBK) {
#pragma unroll
        for (int r = 0; r < 4; ++r) {
            int m = bm + a_m0 + r * 16;
            int row = m;
            if (shiftL > 0) {
                int l = m & (shiftL - 1);
                int base = m - l;
                l += shift;
                if (l < 0) l += shiftL; else if (l >= shiftL) l -= shiftL;
                row = base + l;
            }
            As[a_k][a_m0 + r * 16] = A[(size_t)row * K + (k0 + a_k)];
        }
#pragma unroll
        for (int r = 0; r < 4; ++r) {
            int kk = b_k0 + r * 4;
            Bs[kk][b_n] = Bm[(size_t)(k0 + kk) * N + (bn + b_n)];
        }
        __syncthreads();
#pragma unroll
        for (int kk = 0; kk < GBK; ++kk) {
            f4 av = *(const f4*)&As[kk][ty * 4];
            f4 bv = *(const f4*)&Bs[kk][tx * 4];
#pragma unroll
            for (int i = 0; i < 4; ++i)
#pragma unroll
                for (int j = 0; j < 4; ++j)
                    acc[i][j] = fmaf(av[i], bv[j], acc[i][j]);
        }
        __syncthreads();
    }
#pragma unroll
    for (int i = 0; i < 4; ++i) {
        int m = bm + ty * 4 + i;
#pragma unroll
        for (int j = 0; j < 4; ++j) {
            int n = bn + tx * 4 + j;
            float c = acc[i][j];
            if (bias) c += bias[n];
            if (flags & 2) c = 0.5f * c * (1.0f + erff(c * 0.70710678118654752f));
            size_t o = (size_t)m * N + n;
            if (flags & 1) Cm[o] += c; else Cm[o] = c;
        }
    }
}

// ---------------------------------------------------------------------------
// Autocorrelation scores v2: 128x128 tile, 8x8 register blocking, GBK=32.
// Per-thread values of C elements identical to v1 (same f32 FMA order over k).
// Diagonal reduction: 15 register bins/thread -> wave-private LDS bins
// (atomics contend only within a wave) -> cross-wave sum -> global atomic.
// ---------------------------------------------------------------------------
__global__ __launch_bounds__(256)
void corr_diag(const float* __restrict__ Q, const float* __restrict__ Km,
               float* __restrict__ G)
{
    __shared__ float Qs[CBK][CBM + 4];
    __shared__ float Ks[CBK][CBM + 4];
    __shared__ float diagw[4][256];
    const int tid = threadIdx.x;
    const int b = blockIdx.z;
    const int bt = blockIdx.y * CBM;
    const int bs = blockIdx.x * CBM;
    const float* Qb = Q + ((size_t)b << 19);
    const float* Kb = Km + ((size_t)b << 19);
    const int tx = tid & 15, ty = tid >> 4;
    const int kslot = tid & 7;      // f4 k-chunk 0..7 within 32-wide K-step
    const int sr0 = tid >> 3;       // staging row 0..31 (+32 strides)

    // zero wave-private diag bins once (untouched during K loop)
    float* dz = &diagw[0][0];
    dz[tid] = 0.f; dz[tid + 256] = 0.f; dz[tid + 512] = 0.f; dz[tid + 768] = 0.f;

    float acc[8][8] = {};
    for (int k0 = 0; k0 < 512; k0 += CBK) {
#pragma unroll
        for (int rr = 0; rr < 128; rr += 32) {
            int r = sr0 + rr;
            f4 qv = *(const f4*)&Qb[(size_t)(bt + r) * 512 + k0 + kslot * 4];
            f4 kv = *(const f4*)&Kb[(size_t)(bs + r) * 512 + k0 + kslot * 4];
#pragma unroll
            for (int u = 0; u < 4; ++u) {
                Qs[kslot * 4 + u][r] = qv[u];
                Ks[kslot * 4 + u][r] = kv[u];
            }
        }
        __syncthreads();
#pragma unroll 8
        for (int kk = 0; kk < CBK; ++kk) {
            f4 a0 = *(const f4*)&Qs[kk][ty * 8];
            f4 a1 = *(const f4*)&Qs[kk][ty * 8 + 4];
            f4 b0 = *(const f4*)&Ks[kk][tx * 8];
            f4 b1 = *(const f4*)&Ks[kk][tx * 8 + 4];
            float av[8] = { a0[0], a0[1], a0[2], a0[3], a1[0], a1[1], a1[2], a1[3] };
            float bw[8] = { b0[0], b0[1], b0[2], b0[3], b1[0], b1[1], b1[2], b1[3] };
#pragma unroll
            for (int i = 0; i < 8; ++i)
#pragma unroll
                for (int j = 0; j < 8; ++j)
                    acc[i][j] = fmaf(av[i], bw[j], acc[i][j]);
        }
        __syncthreads();
    }

    // per-thread pre-reduction into 15 diagonal bins (i-j = -7..7)
    float rb[15];
#pragma unroll
    for (int t = 0; t < 15; ++t) rb[t] = 0.f;
#pragma unroll
    for (int i = 0; i < 8; ++i)
#pragma unroll
        for (int j = 0; j < 8; ++j)
            rb[i - j + 7] += acc[i][j];

    const int wv = tid >> 6;
    const int dbase = 8 * (ty - tx) + 120;   // + t  ->  0..254
#pragma unroll
    for (int t = 0; t < 15; ++t)
        atomicAdd(&diagw[wv][dbase + t], rb[t]);
    __syncthreads();
    if (tid < 255) {
        float s = diagw[0][tid] + diagw[1][tid] + diagw[2][tid] + diagw[3][tid];
        int n = (bt - bs + tid - 127) & 1023;
        atomicAdd(&G[(b << 10) + n], s);
    }
}

__global__ __launch_bounds__(256)
void topk_kernel(const float* __restrict__ G, int* __restrict__ delay,
                 float* __restrict__ tc)
{
    __shared__ float vals[1024];
    __shared__ float pv[256];
    __shared__ int   pi[256];
    __shared__ float wsel[TOPK_];
    __shared__ int   isel[TOPK_];
    const int b = blockIdx.x, tid = threadIdx.x;
    for (int i = tid; i < 1024; i += 256) vals[i] = G[(b << 10) + i] * (1.0f / 512.0f);
    __syncthreads();
    for (int it = 0; it < TOPK_; ++it) {
        float bv = -INFINITY; int bi = 0;
        for (int i = tid * 4; i < tid * 4 + 4; ++i) {
            float v = vals[i];
            if (v > bv) { bv = v; bi = i; }
        }
        pv[tid] = bv; pi[tid] = bi;
        __syncthreads();
        if (tid == 0) {
            float m = pv[0]; int mi = pi[0];
            for (int t = 1; t < 256; ++t)
                if (pv[t] > m) { m = pv[t]; mi = pi[t]; }
            wsel[it] = m; isel[it] = mi;
            vals[mi] = -INFINITY;
        }
        __syncthreads();
    }
    if (tid == 0) {
        float m = wsel[0];
#pragma unroll
        for (int i = 1; i < TOPK_; ++i) m = fmaxf(m, wsel[i]);
        float e[TOPK_], s = 0.f;
#pragma unroll
        for (int i = 0; i < TOPK_; ++i) { e[i] = expf(wsel[i] - m); s += e[i]; }
        float inv = 1.0f / s;
#pragma unroll
        for (int i = 0; i < TOPK_; ++i) {
            tc[b * TOPK_ + i] = e[i] * inv;
            delay[b * TOPK_ + i] = isel[i];
        }
    }
}

// out[b,l,d] = sum_i tc[b,i] * V[b,(l+delay)%1024,d], bf16 in/out, 8-wide
__global__ void agg_kernel(const unsigned short* __restrict__ V, const int* __restrict__ delay,
                           const float* __restrict__ tc, unsigned short* __restrict__ out)
{
    int idx = (blockIdx.x * blockDim.x + threadIdx.x) * 8;
    int d = idx & 511;
    int l = (idx >> 9) & 1023;
    int b = idx >> 19;
    const unsigned short* Vb = V + ((size_t)b << 19);
    float s[8] = {};
#pragma unroll
    for (int i = 0; i < TOPK_; ++i) {
        int row = (l + delay[b * TOPK_ + i]) & 1023;
        float w = tc[b * TOPK_ + i];
        u16x8 v = *(const u16x8*)&Vb[((size_t)row << 9) + d];
#pragma unroll
        for (int j = 0; j < 8; ++j)
            s[j] = fmaf(w, bf2f(v[j]), s[j]);
    }
    u16x8 o;
#pragma unroll
    for (int j = 0; j < 8; ++j) o[j] = f2bf(s[j]);
    *(u16x8*)&out[idx] = o;
}

// ---------------------------------------------------------------------------
// series_decomp with optional bf16 dual-out of the seasonal part.
// tmode: 0 seasonal only, 1 write trend, 2 accumulate trend.
// ---------------------------------------------------------------------------
__global__ void decomp_kernel(const float* __restrict__ x, float* __restrict__ seas,
                              unsigned short* __restrict__ seasb,
                              float* __restrict__ trend, int Bn, int Ln, int Ch,
                              int nseg, int tmode)
{
    int idx = blockIdx.x * blockDim.x + threadIdx.x;
    int total = Bn * Ch * nseg;
    if (idx >= total) return;
    int ch = idx % Ch;
    int rest = idx / Ch;
    int seg = rest % nseg;
    int b = rest / nseg;
    int segL = Ln / nseg;
    int l0 = seg * segL;
    const float* xp = x + (size_t)b * Ln * Ch + ch;
    float* sp = seas + (size_t)b * Ln * Ch + ch;
    unsigned short* bp = seasb ? seasb + (size_t)b * Ln * Ch + ch : nullptr;
    float* tp = trend ? trend + (size_t)b * Ln * Ch + ch : nullptr;
    float s = 0.f;
    for (int j = -12; j <= 12; ++j) {
        int t = l0 + j;
        t = t < 0 ? 0 : (t > Ln - 1 ? Ln - 1 : t);
        s += xp[(size_t)t * Ch];
    }
    for (int l = l0; l < l0 + segL; ++l) {
        float mm = s * (1.0f / 25.0f);
        float v = xp[(size_t)l * Ch] - mm;
        sp[(size_t)l * Ch] = v;
        if (bp) bp[(size_t)l * Ch] = f2bf(v);
        if (tmode == 1) tp[(size_t)l * Ch] = mm;
        else if (tmode == 2) tp[(size_t)l * Ch] += mm;
        int ta = l + 13; if (ta > Ln - 1) ta = Ln - 1;
        int ts = l - 12; if (ts < 0) ts = 0;
        s += xp[(size_t)ta * Ch] - xp[(size_t)ts * Ch];
    }
}

// x += pos emb (f32 in place) and write bf16 copy
__global__ void addpos_kernel(float* __restrict__ x, unsigned short* __restrict__ xb)
{
    int idx = blockIdx.x * blockDim.x + threadIdx.x;
    int d = idx & 511;
    int l = (idx >> 9) & 1023;
    int i2 = d & ~1;
    float div = expf(-(float)i2 * 0.017988946039015984f);
    float ang = (float)l * div;
    float v = x[idx] + ((d & 1) ? cosf(ang) : sinf(ang));
    x[idx] = v;
    xb[idx] = f2bf(v);
}

__global__ __launch_bounds__(256)
void lnrow_kernel(const float* __restrict__ x, const float* __restrict__ g,
                  const float* __restrict__ bv, float* __restrict__ out)
{
    __shared__ float sh1[4], sh2[4];
    int row = blockIdx.x, tid = threadIdx.x;
    const float* xr = x + ((size_t)row << 9);
    float v0 = xr[tid], v1 = xr[tid + 256];
    float s = v0 + v1, q = v0 * v0 + v1 * v1;
#pragma unroll
    for (int o = 32; o > 0; o >>= 1) {
        s += __shfl_down(s, o, 64);
        q += __shfl_down(q, o, 64);
    }
    int wid = tid >> 6;
    if ((tid & 63) == 0) { sh1[wid] = s; sh2[wid] = q; }
    __syncthreads();
    if (tid == 0) {
        sh1[0] = sh1[0] + sh1[1] + sh1[2] + sh1[3];
        sh2[0] = sh2[0] + sh2[1] + sh2[2] + sh2[3];
    }
    __syncthreads();
    float mu = sh1[0] * (1.0f / 512.0f);
    float var = sh2[0] * (1.0f / 512.0f) - mu * mu;
    float inv = rsqrtf(var + 1e-5f);
    out[((size_t)row << 9) + tid] = (v0 - mu) * inv * g[tid] + bv[tid];
    out[((size_t)row << 9) + tid + 256] = (v1 - mu) * inv * g[tid + 256] + bv[tid + 256];
}

__global__ void colmean_kernel(const float* __restrict__ x, float* __restrict__ m)
{
    int idx = blockIdx.x * blockDim.x + threadIdx.x;
    if (idx >= B_ * D_) return;
    int b = idx >> 9, d = idx & 511;
    const float* xp = x + ((size_t)b << 19) + d;
    float s = 0.f;
    for (int l = 0; l < L_; ++l) s += xp[(size_t)l << 9];
    m[idx] = s * (1.0f / 1024.0f);
}

// out_bf16 = x - colmean (encoder output, bf16 only)
__global__ void colsub_kernel(const float* __restrict__ x, const float* __restrict__ m,
                              unsigned short* __restrict__ out)
{
    int idx = blockIdx.x * blockDim.x + threadIdx.x;
    int d = idx & 511;
    int b = idx >> 19;
    out[idx] = f2bf(x[idx] - m[(b << 9) + d]);
}

__global__ void meanx_kernel(const float* __restrict__ x, float* __restrict__ m)
{
    int idx = blockIdx.x * blockDim.x + threadIdx.x;
    if (idx >= B_ * C_) return;
    int b = idx >> 6, c = idx & 63;
    const float* xp = x + (size_t)b * L_ * C_ + c;
    float s = 0.f;
    for (int l = 0; l < L_; ++l) s += xp[(size_t)l << 6];
    m[idx] = s * (1.0f / 1024.0f);
}

__global__ void builddec_kernel(const float* __restrict__ trenc, const float* __restrict__ seenc,
                                const float* __restrict__ meanc,
                                float* __restrict__ trend, float* __restrict__ seasin)
{
    int idx = blockIdx.x * blockDim.x + threadIdx.x;
    int c = idx & 63;
    int l = (idx >> 6) & 1023;
    int b = idx >> 16;
    if (l < 512) {
        int src = (b << 16) + ((512 + l) << 6) + c;
        trend[idx] = trenc[src];
        seasin[idx] = seenc[src];
    } else {
        trend[idx] = meanc[(b << 6) + c];
        seasin[idx] = 0.f;
    }
}

__global__ void final_kernel(const float* __restrict__ trend, const float* __restrict__ s64,
                             float* __restrict__ out)
{
    int idx = blockIdx.x * blockDim.x + threadIdx.x;
    int c = idx & 63;
    int l = (idx >> 6) & 511;
    int b = idx >> 15;
    int src = (b << 16) + ((512 + l) << 6) + c;
    out[idx] = trend[src] + s64[src];
}

__global__ void zero_kernel(float* __restrict__ p, int n)
{
    int idx = blockIdx.x * blockDim.x + threadIdx.x;
    if (idx < n) p[idx] = 0.f;
}

// ---------------------------------------------------------------------------
extern "C" void kernel_launch(void* const* d_in, const int* in_sizes, int n_in,
                              void* d_out, int out_size, void* d_ws, size_t ws_size,
                              hipStream_t stream)
{
    auto F = [&](int i) { return (const float*)d_in[i]; };
    const float* x_enc     = F(0);
    const float* enc_emb_w = F(2);
    const float* dec_emb_w = F(3);
    const float* enc_Wq = F(4);  const float* enc_bq = F(5);
    const float* dsa_Wq = F(6);  const float* dsa_bq = F(7);
    const float* dca_Wq = F(8);  const float* dca_bq = F(9);
    const float* enc_Wk = F(10); const float* enc_bk = F(11);
    const float* dsa_Wk = F(12); const float* dsa_bk = F(13);
    const float* dca_Wk = F(14); const float* dca_bk = F(15);
    const float* enc_Wv = F(16); const float* enc_bv = F(17);
    const float* dsa_Wv = F(18); const float* dsa_bv = F(19);
    const float* dca_Wv = F(20); const float* dca_bv = F(21);
    const float* enc_Wo = F(22); const float* enc_bo = F(23);
    const float* dsa_Wo = F(24); const float* dsa_bo = F(25);
    const float* dca_Wo = F(26); const float* dca_bo = F(27);
    const float* enc_ff1 = F(28); const float* enc_ff2 = F(29);
    const float* enc_ng = F(30);  const float* enc_nb = F(31);
    const float* dec_ff1 = F(32); const float* dec_ff2 = F(33);
    const float* dec_trend_w = F(34);
    const float* proj_w = F(35);  const float* proj_b = F(36);

    constexpr size_t F512 = (size_t)B_ * L_ * D_;   // 8388608
    constexpr size_t F64  = (size_t)B_ * L_ * C_;   // 1048576
    constexpr size_t SMALL = 1024 + 16384 + 320 + 320 + 8192;
    constexpr size_t WTSN = 2 * 1024 * 1024;        // bf16 weight scratch elems
    size_t need = (5 * F512 + 2 * F64 + SMALL) * 4 + (4 * F512 + WTSN) * 2;
    if (ws_size < need) return;

    float* X      = (float*)d_ws;
    float* T1     = X + F512;
    float* T2     = T1 + F512;
    float* T3     = T2 + F512;
    float* TSUM   = T3 + F512;
    float* SEASIN = TSUM + F512;
    float* TREND  = SEASIN + F64;
    float* MEANC  = TREND + F64;
    float* G      = MEANC + 1024;
    float* TCW    = G + 16384;
    int*   DEL    = (int*)(TCW + 320);
    float* LNMEAN = (float*)(DEL + 320);
    unsigned short* AB  = (unsigned short*)(LNMEAN + 8192);
    unsigned short* EB  = AB + F512;
    unsigned short* VB  = EB + F512;
    unsigned short* HB  = VB + F512;
    unsigned short* WTS = HB + F512;
    float* OUT = (float*)d_out;

    const int M = B_ * L_;  // 16384

    auto gemm = [&](const float* A, const float* Bm, float* Cm, const float* bias,
                    int Mm, int Nn, int Kk, int flags, int shift = 0, int shiftL = 0) {
        dim3 g(Nn / GBN, Mm / GBM);
        gemm_f32<<<g, 256, 0, stream>>>(A, Bm, Cm, bias, Mm, Nn, Kk, flags, shift, shiftL);
    };
    auto mgemm = [&](const unsigned short* A, const unsigned short* Bt, float* Cf,
                     unsigned short* Cb, const float* bias, int Mm, int Nn, int Kk, int flags) {
        dim3 g(Nn / 128, Mm / 128);
        gemm_bf16<<<g, 256, 0, stream>>>(A, Bt, Cf, Cb, bias, Mm, Nn, Kk, flags);
    };
    auto tcast = [&](const float* W, unsigned short* Wt, int R, int Cc) {
        tcast_kernel<<<dim3(Cc / 32, R / 32), 256, 0, stream>>>(W, Wt, R, Cc);
    };
    auto attn = [&](const unsigned short* qin, const unsigned short* kvin,
                    const float* Wq, const float* bq, const float* Wk, const float* bk,
                    const float* Wv, const float* bvp, const float* Wo, const float* bo,
                    float* resid) {
        unsigned short* Wt0 = WTS;
        unsigned short* Wt1 = WTS + 262144;
        unsigned short* Wt2 = WTS + 524288;
        unsigned short* Wt3 = WTS + 786432;
        tcast(Wq, Wt0, 512, 512);
        tcast(Wk, Wt1, 512, 512);
        tcast(Wv, Wt2, 512, 512);
        tcast(Wo, Wt3, 512, 512);
        mgemm(qin,  Wt0, T2, nullptr, bq, M, 512, 512, 0);
        mgemm(kvin, Wt1, T3, nullptr, bk, M, 512, 512, 0);
        mgemm(kvin, Wt2, nullptr, VB, bvp, M, 512, 512, 0);
        zero_kernel<<<16384 / 256, 256, 0, stream>>>(G, 16384);
        corr_diag<<<dim3(8, 8, 16), 256, 0, stream>>>(T2, T3, G);
        topk_kernel<<<16, 256, 0, stream>>>(G, DEL, TCW);
        agg_kernel<<<(int)(F512 / 8 / 256), 256, 0, stream>>>(VB, DEL, TCW, HB);
        mgemm(HB, Wt3, resid, nullptr, bo, M, 512, 512, 1);
    };
    auto ffblock = [&](const unsigned short* xin, const float* W1, const float* W2, float* resid) {
        unsigned short* Wf1 = WTS;
        unsigned short* Wf2 = WTS + 1048576;
        tcast(W1, Wf1, 512, 2048);
        tcast(W2, Wf2, 2048, 512);
        for (int c = 0; c < 4; ++c) {
            mgemm(xin + (size_t)c * 4096 * 512, Wf1, nullptr, HB, nullptr, 4096, 2048, 512, 2);
            mgemm(HB, Wf2, resid + (size_t)c * 4096 * 512, nullptr, nullptr, 4096, 512, 2048, 1);
        }
    };

    // ---------------- prep: decomposition of x_enc, decoder inits -----------
    float* SEENC = T2;  // aliases: prep phase only
    float* TRENC = T3;
    decomp_kernel<<<(B_ * C_ * 8 + 255) / 256, 256, 0, stream>>>(x_enc, SEENC, nullptr, TRENC, B_, L_, C_, 8, 1);
    meanx_kernel<<<(B_ * C_ + 255) / 256, 256, 0, stream>>>(x_enc, MEANC);
    builddec_kernel<<<(int)(F64 / 256), 256, 0, stream>>>(TRENC, SEENC, MEANC, TREND, SEASIN);

    // ---------------- encoder ----------------------------------------------
    gemm(x_enc, enc_emb_w,               X, nullptr, M, D_, C_, 0, -1, L_);
    gemm(x_enc, enc_emb_w + 1 * C_ * D_, X, nullptr, M, D_, C_, 1,  0, L_);
    gemm(x_enc, enc_emb_w + 2 * C_ * D_, X, nullptr, M, D_, C_, 1,  1, L_);
    addpos_kernel<<<(int)(F512 / 256), 256, 0, stream>>>(X, AB);

    for (int l = 0; l < 2; ++l) {
        attn(AB, AB,
             enc_Wq + (size_t)l * D_ * D_, enc_bq + l * D_,
             enc_Wk + (size_t)l * D_ * D_, enc_bk + l * D_,
             enc_Wv + (size_t)l * D_ * D_, enc_bv + l * D_,
             enc_Wo + (size_t)l * D_ * D_, enc_bo + l * D_, X);
        decomp_kernel<<<(B_ * D_ * 8 + 255) / 256, 256, 0, stream>>>(X, T1, AB, nullptr, B_, L_, D_, 8, 0);
        ffblock(AB, enc_ff1 + (size_t)l * D_ * DFF_, enc_ff2 + (size_t)l * DFF_ * D_, T1);
        decomp_kernel<<<(B_ * D_ * 8 + 255) / 256, 256, 0, stream>>>(T1, X, AB, nullptr, B_, L_, D_, 8, 0);
    }
    lnrow_kernel<<<M, 256, 0, stream>>>(X, enc_ng, enc_nb, T1);
    colmean_kernel<<<(B_ * D_ + 255) / 256, 256, 0, stream>>>(T1, LNMEAN);
    colsub_kernel<<<(int)(F512 / 256), 256, 0, stream>>>(T1, LNMEAN, EB);

    // ---------------- decoder ----------------------------------------------
    float* XD = X;
    gemm(SEASIN, dec_emb_w,               XD, nullptr, M, D_, C_, 0, -1, L_);
    gemm(SEASIN, dec_emb_w + 1 * C_ * D_, XD, nullptr, M, D_, C_, 1,  0, L_);
    gemm(SEASIN, dec_emb_w + 2 * C_ * D_, XD, nullptr, M, D_, C_, 1,  1, L_);
    addpos_kernel<<<(int)(F512 / 256), 256, 0, stream>>>(XD, AB);

    attn(AB, AB, dsa_Wq, dsa_bq, dsa_Wk, dsa_bk, dsa_Wv, dsa_bv, dsa_Wo, dsa_bo, XD);
    decomp_kernel<<<(B_ * D_ * 8 + 255) / 256, 256, 0, stream>>>(XD, T1, AB, TSUM, B_, L_, D_, 8, 1);

    attn(AB, EB, dca_Wq, dca_bq, dca_Wk, dca_bk, dca_Wv, dca_bv, dca_Wo, dca_bo, T1);
    decomp_kernel<<<(B_ * D_ * 8 + 255) / 256, 256, 0, stream>>>(T1, XD, AB, TSUM, B_, L_, D_, 8, 2);

    ffblock(AB, dec_ff1, dec_ff2, XD);
    decomp_kernel<<<(B_ * D_ * 8 + 255) / 256, 256, 0, stream>>>(XD, T1, nullptr, TSUM, B_, L_, D_, 8, 2);

    // trend projection conv (3 taps) accumulated onto TREND
    gemm(TSUM, dec_trend_w,               TREND, nullptr, M, C_, D_, 1, -1, L_);
    gemm(TSUM, dec_trend_w + 1 * D_ * C_, TREND, nullptr, M, C_, D_, 1,  0, L_);
    gemm(TSUM, dec_trend_w + 2 * D_ * C_, TREND, nullptr, M, C_, D_, 1,  1, L_);

    // seasonal projection + final output
    float* S64 = T2;  // T2 free by now
    gemm(T1, proj_w, S64, proj_b, M, C_, D_, 0);
    final_kernel<<<(B_ * 512 * C_) / 256, 256, 0, stream>>>(TREND, S64, OUT);
}

// Round 4
// 3731.802 us; speedup vs baseline: 2.4347x; 1.2441x over previous
//
#include <hip/hip_runtime.h>
#include <math.h>

#define B_   16
#define L_   1024
#define C_   64
#define D_   512
#define DFF_ 2048
#define TOPK_ 20

constexpr int GBM = 64, GBN = 64, GBK = 16;
constexpr int CBM = 128, CBK = 32;

typedef float f4 __attribute__((ext_vector_type(4)));
typedef float f32x4 __attribute__((ext_vector_type(4)));
typedef short bf16x8 __attribute__((ext_vector_type(8)));
typedef unsigned short u16x8 __attribute__((ext_vector_type(8)));

__device__ __forceinline__ unsigned short f2bf(float f) {
    union { float f; unsigned u; } a; a.f = f;
    unsigned r = a.u + 0x7fff + ((a.u >> 16) & 1);
    return (unsigned short)(r >> 16);
}
__device__ __forceinline__ float bf2f(unsigned short h) {
    union { unsigned u; float f; } a; a.u = ((unsigned)h) << 16;
    return a.f;
}

__device__ __forceinline__ void gld16(const void* g, void* l) {
    __builtin_amdgcn_global_load_lds(
        (const __attribute__((address_space(1))) unsigned int*)g,
        (__attribute__((address_space(3))) unsigned int*)l, 16, 0, 0);
}

// ---------------------------------------------------------------------------
// bf16 MFMA GEMM: C[M,N] = op(A[M,K] @ B[K,N] + bias)
// A: bf16 [M][K] row-major. Bt: bf16 [N][K] (pre-transposed weight).
// Cf: f32 out (flags&1: accumulate). Cb: bf16 out. flags&2: exact GELU.
// ---------------------------------------------------------------------------
__global__ __launch_bounds__(256)
void gemm_bf16(const unsigned short* __restrict__ A, const unsigned short* __restrict__ Bt,
               float* __restrict__ Cf, unsigned short* __restrict__ Cb,
               const float* __restrict__ bias, int M, int N, int K, int flags)
{
    __shared__ unsigned short As[128 * 32];
    __shared__ unsigned short Bs[128 * 32];
    const int tid = threadIdx.x;
    const int wave = tid >> 6, lane = tid & 63;
    const int bm = blockIdx.y * 128, bn = blockIdx.x * 128;
    const int wm = (wave >> 1) << 6, wn = (wave & 1) << 6;

    const int r0 = (wave << 5) + (lane >> 2);
    const int kq = (lane & 3) << 3;
    const unsigned short* Ap0 = A + (size_t)(bm + r0) * K + kq;
    const unsigned short* Ap1 = Ap0 + (size_t)16 * K;
    const unsigned short* Bp0 = Bt + (size_t)(bn + r0) * K + kq;
    const unsigned short* Bp1 = Bp0 + (size_t)16 * K;
    unsigned short* Al0 = &As[(wave << 5) * 32];
    unsigned short* Al1 = &As[((wave << 5) + 16) * 32];
    unsigned short* Bl0 = &Bs[(wave << 5) * 32];
    unsigned short* Bl1 = &Bs[((wave << 5) + 16) * 32];

    const int la = lane & 15, hi = lane >> 4;
    f32x4 acc[4][4] = {};

    for (int k0 = 0; k0 < K; k0 += 32) {
        gld16(Ap0 + k0, Al0);
        gld16(Ap1 + k0, Al1);
        gld16(Bp0 + k0, Bl0);
        gld16(Bp1 + k0, Bl1);
        __syncthreads();
        bf16x8 a[4], b[4];
#pragma unroll
        for (int i = 0; i < 4; ++i) {
            a[i] = *(const bf16x8*)&As[(wm + i * 16 + la) * 32 + hi * 8];
            b[i] = *(const bf16x8*)&Bs[(wn + i * 16 + la) * 32 + hi * 8];
        }
#pragma unroll
        for (int mi = 0; mi < 4; ++mi)
#pragma unroll
            for (int ni = 0; ni < 4; ++ni)
                acc[mi][ni] = __builtin_amdgcn_mfma_f32_16x16x32_bf16(a[mi], b[ni], acc[mi][ni], 0, 0, 0);
        __syncthreads();
    }

#pragma unroll
    for (int mi = 0; mi < 4; ++mi) {
#pragma unroll
        for (int r = 0; r < 4; ++r) {
            int m = bm + wm + mi * 16 + hi * 4 + r;
#pragma unroll
            for (int ni = 0; ni < 4; ++ni) {
                int n = bn + wn + ni * 16 + la;
                float c = acc[mi][ni][r];
                if (bias) c += bias[n];
                if (flags & 2) c = 0.5f * c * (1.0f + erff(c * 0.70710678118654752f));
                size_t o = (size_t)m * N + n;
                if (Cf) { if (flags & 1) Cf[o] += c; else Cf[o] = c; }
                if (Cb) Cb[o] = f2bf(c);
            }
        }
    }
}

// transpose + cast: W [R][Cc] f32 -> Wt [Cc][R] bf16
__global__ __launch_bounds__(256)
void tcast_kernel(const float* __restrict__ W, unsigned short* __restrict__ Wt, int R, int Cc)
{
    __shared__ float t[32][33];
    int bx = blockIdx.x * 32, by = blockIdx.y * 32;
    int tx = threadIdx.x & 31, ty = threadIdx.x >> 5;
#pragma unroll
    for (int i = 0; i < 32; i += 8)
        t[ty + i][tx] = W[(size_t)(by + ty + i) * Cc + bx + tx];
    __syncthreads();
#pragma unroll
    for (int i = 0; i < 32; i += 8)
        Wt[(size_t)(bx + ty + i) * R + by + tx] = f2bf(t[tx][ty + i]);
}

// ---------------------------------------------------------------------------
// Generic f32 GEMM (embeddings / trend conv / proj).
// flags bit0: accumulate, bit1: GELU. shiftL>0: circular A-row remap.
// ---------------------------------------------------------------------------
__global__ __launch_bounds__(256)
void gemm_f32(const float* __restrict__ A, const float* __restrict__ Bm,
              float* __restrict__ Cm, const float* __restrict__ bias,
              int M, int N, int K, int flags, int shift, int shiftL)
{
    __shared__ float As[GBK][GBM + 4];
    __shared__ float Bs[GBK][GBN + 4];
    const int tid = threadIdx.x;
    const int bm = blockIdx.y * GBM;
    const int bn = blockIdx.x * GBN;
    const int tx = tid & 15, ty = tid >> 4;
    const int a_k = tid & 15, a_m0 = tid >> 4;
    const int b_n = tid & 63, b_k0 = tid >> 6;
    float acc[4][4] = {};
    for (int k0 = 0; k0 < K; k0 += GBK) {
#pragma unroll
        for (int r = 0; r < 4; ++r) {
            int m = bm + a_m0 + r * 16;
            int row = m;
            if (shiftL > 0) {
                int l = m & (shiftL - 1);
                int base = m - l;
                l += shift;
                if (l < 0) l += shiftL; else if (l >= shiftL) l -= shiftL;
                row = base + l;
            }
            As[a_k][a_m0 + r * 16] = A[(size_t)row * K + (k0 + a_k)];
        }
#pragma unroll
        for (int r = 0; r < 4; ++r) {
            int kk = b_k0 + r * 4;
            Bs[kk][b_n] = Bm[(size_t)(k0 + kk) * N + (bn + b_n)];
        }
        __syncthreads();
#pragma unroll
        for (int kk = 0; kk < GBK; ++kk) {
            f4 av = *(const f4*)&As[kk][ty * 4];
            f4 bv = *(const f4*)&Bs[kk][tx * 4];
#pragma unroll
            for (int i = 0; i < 4; ++i)
#pragma unroll
                for (int j = 0; j < 4; ++j)
                    acc[i][j] = fmaf(av[i], bv[j], acc[i][j]);
        }
        __syncthreads();
    }
#pragma unroll
    for (int i = 0; i < 4; ++i) {
        int m = bm + ty * 4 + i;
#pragma unroll
        for (int j = 0; j < 4; ++j) {
            int n = bn + tx * 4 + j;
            float c = acc[i][j];
            if (bias) c += bias[n];
            if (flags & 2) c = 0.5f * c * (1.0f + erff(c * 0.70710678118654752f));
            size_t o = (size_t)m * N + n;
            if (flags & 1) Cm[o] += c; else Cm[o] = c;
        }
    }
}

// ---------------------------------------------------------------------------
// Autocorrelation scores v2: 128x128 tile, 8x8 register blocking, GBK=32.
// ---------------------------------------------------------------------------
__global__ __launch_bounds__(256)
void corr_diag(const float* __restrict__ Q, const float* __restrict__ Km,
               float* __restrict__ G)
{
    __shared__ float Qs[CBK][CBM + 4];
    __shared__ float Ks[CBK][CBM + 4];
    __shared__ float diagw[4][256];
    const int tid = threadIdx.x;
    const int b = blockIdx.z;
    const int bt = blockIdx.y * CBM;
    const int bs = blockIdx.x * CBM;
    const float* Qb = Q + ((size_t)b << 19);
    const float* Kb = Km + ((size_t)b << 19);
    const int tx = tid & 15, ty = tid >> 4;
    const int kslot = tid & 7;
    const int sr0 = tid >> 3;

    float* dz = &diagw[0][0];
    dz[tid] = 0.f; dz[tid + 256] = 0.f; dz[tid + 512] = 0.f; dz[tid + 768] = 0.f;

    float acc[8][8] = {};
    for (int k0 = 0; k0 < 512; k0 += CBK) {
#pragma unroll
        for (int rr = 0; rr < 128; rr += 32) {
            int r = sr0 + rr;
            f4 qv = *(const f4*)&Qb[(size_t)(bt + r) * 512 + k0 + kslot * 4];
            f4 kv = *(const f4*)&Kb[(size_t)(bs + r) * 512 + k0 + kslot * 4];
#pragma unroll
            for (int u = 0; u < 4; ++u) {
                Qs[kslot * 4 + u][r] = qv[u];
                Ks[kslot * 4 + u][r] = kv[u];
            }
        }
        __syncthreads();
#pragma unroll 8
        for (int kk = 0; kk < CBK; ++kk) {
            f4 a0 = *(const f4*)&Qs[kk][ty * 8];
            f4 a1 = *(const f4*)&Qs[kk][ty * 8 + 4];
            f4 b0 = *(const f4*)&Ks[kk][tx * 8];
            f4 b1 = *(const f4*)&Ks[kk][tx * 8 + 4];
            float av[8] = { a0[0], a0[1], a0[2], a0[3], a1[0], a1[1], a1[2], a1[3] };
            float bw[8] = { b0[0], b0[1], b0[2], b0[3], b1[0], b1[1], b1[2], b1[3] };
#pragma unroll
            for (int i = 0; i < 8; ++i)
#pragma unroll
                for (int j = 0; j < 8; ++j)
                    acc[i][j] = fmaf(av[i], bw[j], acc[i][j]);
        }
        __syncthreads();
    }

    float rb[15];
#pragma unroll
    for (int t = 0; t < 15; ++t) rb[t] = 0.f;
#pragma unroll
    for (int i = 0; i < 8; ++i)
#pragma unroll
        for (int j = 0; j < 8; ++j)
            rb[i - j + 7] += acc[i][j];

    const int wv = tid >> 6;
    const int dbase = 8 * (ty - tx) + 120;
#pragma unroll
    for (int t = 0; t < 15; ++t)
        atomicAdd(&diagw[wv][dbase + t], rb[t]);
    __syncthreads();
    if (tid < 255) {
        float s = diagw[0][tid] + diagw[1][tid] + diagw[2][tid] + diagw[3][tid];
        int n = (bt - bs + tid - 127) & 1023;
        atomicAdd(&G[(b << 10) + n], s);
    }
}

// ---------------------------------------------------------------------------
// Per-batch top-20 + softmax, parallel argmax.
// Tie semantics identical to sequential scan: strict > picks lowest index
// among ties (combine rule prefers smaller index on equal value).
// ---------------------------------------------------------------------------
__global__ __launch_bounds__(256)
void topk_kernel(const float* __restrict__ G, int* __restrict__ delay,
                 float* __restrict__ tc)
{
    __shared__ float vals[1024];
    __shared__ float pw[4];
    __shared__ int   pwi[4];
    __shared__ float wsel[TOPK_];
    __shared__ int   isel[TOPK_];
    const int b = blockIdx.x, tid = threadIdx.x;
    const int lane = tid & 63, wid = tid >> 6;
    for (int i = tid; i < 1024; i += 256) vals[i] = G[(b << 10) + i] * (1.0f / 512.0f);
    __syncthreads();
    for (int it = 0; it < TOPK_; ++it) {
        float bv = -INFINITY; int bi = 0;
#pragma unroll
        for (int u = 0; u < 4; ++u) {
            int i = tid * 4 + u;
            float v = vals[i];
            if (v > bv) { bv = v; bi = i; }
        }
#pragma unroll
        for (int o = 32; o > 0; o >>= 1) {
            float ov = __shfl_xor(bv, o, 64);
            int   oi = __shfl_xor(bi, o, 64);
            if (ov > bv || (ov == bv && oi < bi)) { bv = ov; bi = oi; }
        }
        if (lane == 0) { pw[wid] = bv; pwi[wid] = bi; }
        __syncthreads();
        if (tid == 0) {
            float m = pw[0]; int mi = pwi[0];
#pragma unroll
            for (int t = 1; t < 4; ++t)
                if (pw[t] > m || (pw[t] == m && pwi[t] < mi)) { m = pw[t]; mi = pwi[t]; }
            wsel[it] = m; isel[it] = mi;
            vals[mi] = -INFINITY;
        }
        __syncthreads();
    }
    if (tid == 0) {
        float m = wsel[0];
#pragma unroll
        for (int i = 1; i < TOPK_; ++i) m = fmaxf(m, wsel[i]);
        float e[TOPK_], s = 0.f;
#pragma unroll
        for (int i = 0; i < TOPK_; ++i) { e[i] = expf(wsel[i] - m); s += e[i]; }
        float inv = 1.0f / s;
#pragma unroll
        for (int i = 0; i < TOPK_; ++i) {
            tc[b * TOPK_ + i] = e[i] * inv;
            delay[b * TOPK_ + i] = isel[i];
        }
    }
}

// out[b,l,d] = sum_i tc[b,i] * V[b,(l+delay)%1024,d], bf16 in/out, 8-wide
__global__ void agg_kernel(const unsigned short* __restrict__ V, const int* __restrict__ delay,
                           const float* __restrict__ tc, unsigned short* __restrict__ out)
{
    int idx = (blockIdx.x * blockDim.x + threadIdx.x) * 8;
    int d = idx & 511;
    int l = (idx >> 9) & 1023;
    int b = idx >> 19;
    const unsigned short* Vb = V + ((size_t)b << 19);
    float s[8] = {};
#pragma unroll
    for (int i = 0; i < TOPK_; ++i) {
        int row = (l + delay[b * TOPK_ + i]) & 1023;
        float w = tc[b * TOPK_ + i];
        u16x8 v = *(const u16x8*)&Vb[((size_t)row << 9) + d];
#pragma unroll
        for (int j = 0; j < 8; ++j)
            s[j] = fmaf(w, bf2f(v[j]), s[j]);
    }
    u16x8 o;
#pragma unroll
    for (int j = 0; j < 8; ++j) o[j] = f2bf(s[j]);
    *(u16x8*)&out[idx] = o;
}

// ---------------------------------------------------------------------------
// series_decomp with optional bf16 dual-out of the seasonal part.
// ---------------------------------------------------------------------------
__global__ void decomp_kernel(const float* __restrict__ x, float* __restrict__ seas,
                              unsigned short* __restrict__ seasb,
                              float* __restrict__ trend, int Bn, int Ln, int Ch,
                              int nseg, int tmode)
{
    int idx = blockIdx.x * blockDim.x + threadIdx.x;
    int total = Bn * Ch * nseg;
    if (idx >= total) return;
    int ch = idx % Ch;
    int rest = idx / Ch;
    int seg = rest % nseg;
    int b = rest / nseg;
    int segL = Ln / nseg;
    int l0 = seg * segL;
    const float* xp = x + (size_t)b * Ln * Ch + ch;
    float* sp = seas + (size_t)b * Ln * Ch + ch;
    unsigned short* bp = seasb ? seasb + (size_t)b * Ln * Ch + ch : nullptr;
    float* tp = trend ? trend + (size_t)b * Ln * Ch + ch : nullptr;
    float s = 0.f;
    for (int j = -12; j <= 12; ++j) {
        int t = l0 + j;
        t = t < 0 ? 0 : (t > Ln - 1 ? Ln - 1 : t);
        s += xp[(size_t)t * Ch];
    }
    for (int l = l0; l < l0 + segL; ++l) {
        float mm = s * (1.0f / 25.0f);
        float v = xp[(size_t)l * Ch] - mm;
        sp[(size_t)l * Ch] = v;
        if (bp) bp[(size_t)l * Ch] = f2bf(v);
        if (tmode == 1) tp[(size_t)l * Ch] = mm;
        else if (tmode == 2) tp[(size_t)l * Ch] += mm;
        int ta = l + 13; if (ta > Ln - 1) ta = Ln - 1;
        int ts = l - 12; if (ts < 0) ts = 0;
        s += xp[(size_t)ta * Ch] - xp[(size_t)ts * Ch];
    }
}

// x += pos emb (f32 in place) and write bf16 copy
__global__ void addpos_kernel(float* __restrict__ x, unsigned short* __restrict__ xb)
{
    int idx = blockIdx.x * blockDim.x + threadIdx.x;
    int d = idx & 511;
    int l = (idx >> 9) & 1023;
    int i2 = d & ~1;
    float div = expf(-(float)i2 * 0.017988946039015984f);
    float ang = (float)l * div;
    float v = x[idx] + ((d & 1) ? cosf(ang) : sinf(ang));
    x[idx] = v;
    xb[idx] = f2bf(v);
}

__global__ __launch_bounds__(256)
void lnrow_kernel(const float* __restrict__ x, const float* __restrict__ g,
                  const float* __restrict__ bv, float* __restrict__ out)
{
    __shared__ float sh1[4], sh2[4];
    int row = blockIdx.x, tid = threadIdx.x;
    const float* xr = x + ((size_t)row << 9);
    float v0 = xr[tid], v1 = xr[tid + 256];
    float s = v0 + v1, q = v0 * v0 + v1 * v1;
#pragma unroll
    for (int o = 32; o > 0; o >>= 1) {
        s += __shfl_down(s, o, 64);
        q += __shfl_down(q, o, 64);
    }
    int wid = tid >> 6;
    if ((tid & 63) == 0) { sh1[wid] = s; sh2[wid] = q; }
    __syncthreads();
    if (tid == 0) {
        sh1[0] = sh1[0] + sh1[1] + sh1[2] + sh1[3];
        sh2[0] = sh2[0] + sh2[1] + sh2[2] + sh2[3];
    }
    __syncthreads();
    float mu = sh1[0] * (1.0f / 512.0f);
    float var = sh2[0] * (1.0f / 512.0f) - mu * mu;
    float inv = rsqrtf(var + 1e-5f);
    out[((size_t)row << 9) + tid] = (v0 - mu) * inv * g[tid] + bv[tid];
    out[((size_t)row << 9) + tid + 256] = (v1 - mu) * inv * g[tid + 256] + bv[tid + 256];
}

__global__ void colmean_kernel(const float* __restrict__ x, float* __restrict__ m)
{
    int idx = blockIdx.x * blockDim.x + threadIdx.x;
    if (idx >= B_ * D_) return;
    int b = idx >> 9, d = idx & 511;
    const float* xp = x + ((size_t)b << 19) + d;
    float s = 0.f;
    for (int l = 0; l < L_; ++l) s += xp[(size_t)l << 9];
    m[idx] = s * (1.0f / 1024.0f);
}

// out_bf16 = x - colmean (encoder output, bf16 only)
__global__ void colsub_kernel(const float* __restrict__ x, const float* __restrict__ m,
                              unsigned short* __restrict__ out)
{
    int idx = blockIdx.x * blockDim.x + threadIdx.x;
    int d = idx & 511;
    int b = idx >> 19;
    out[idx] = f2bf(x[idx] - m[(b << 9) + d]);
}

__global__ void meanx_kernel(const float* __restrict__ x, float* __restrict__ m)
{
    int idx = blockIdx.x * blockDim.x + threadIdx.x;
    if (idx >= B_ * C_) return;
    int b = idx >> 6, c = idx & 63;
    const float* xp = x + (size_t)b * L_ * C_ + c;
    float s = 0.f;
    for (int l = 0; l < L_; ++l) s += xp[(size_t)l << 6];
    m[idx] = s * (1.0f / 1024.0f);
}

__global__ void builddec_kernel(const float* __restrict__ trenc, const float* __restrict__ seenc,
                                const float* __restrict__ meanc,
                                float* __restrict__ trend, float* __restrict__ seasin)
{
    int idx = blockIdx.x * blockDim.x + threadIdx.x;
    int c = idx & 63;
    int l = (idx >> 6) & 1023;
    int b = idx >> 16;
    if (l < 512) {
        int src = (b << 16) + ((512 + l) << 6) + c;
        trend[idx] = trenc[src];
        seasin[idx] = seenc[src];
    } else {
        trend[idx] = meanc[(b << 6) + c];
        seasin[idx] = 0.f;
    }
}

__global__ void final_kernel(const float* __restrict__ trend, const float* __restrict__ s64,
                             float* __restrict__ out)
{
    int idx = blockIdx.x * blockDim.x + threadIdx.x;
    int c = idx & 63;
    int l = (idx >> 6) & 511;
    int b = idx >> 15;
    int src = (b << 16) + ((512 + l) << 6) + c;
    out[idx] = trend[src] + s64[src];
}

__global__ void zero_kernel(float* __restrict__ p, int n)
{
    int idx = blockIdx.x * blockDim.x + threadIdx.x;
    if (idx < n) p[idx] = 0.f;
}

// ---------------------------------------------------------------------------
extern "C" void kernel_launch(void* const* d_in, const int* in_sizes, int n_in,
                              void* d_out, int out_size, void* d_ws, size_t ws_size,
                              hipStream_t stream)
{
    auto F = [&](int i) { return (const float*)d_in[i]; };
    const float* x_enc     = F(0);
    const float* enc_emb_w = F(2);
    const float* dec_emb_w = F(3);
    const float* enc_Wq = F(4);  const float* enc_bq = F(5);
    const float* dsa_Wq = F(6);  const float* dsa_bq = F(7);
    const float* dca_Wq = F(8);  const float* dca_bq = F(9);
    const float* enc_Wk = F(10); const float* enc_bk = F(11);
    const float* dsa_Wk = F(12); const float* dsa_bk = F(13);
    const float* dca_Wk = F(14); const float* dca_bk = F(15);
    const float* enc_Wv = F(16); const float* enc_bv = F(17);
    const float* dsa_Wv = F(18); const float* dsa_bv = F(19);
    const float* dca_Wv = F(20); const float* dca_bv = F(21);
    const float* enc_Wo = F(22); const float* enc_bo = F(23);
    const float* dsa_Wo = F(24); const float* dsa_bo = F(25);
    const float* dca_Wo = F(26); const float* dca_bo = F(27);
    const float* enc_ff1 = F(28); const float* enc_ff2 = F(29);
    const float* enc_ng = F(30);  const float* enc_nb = F(31);
    const float* dec_ff1 = F(32); const float* dec_ff2 = F(33);
    const float* dec_trend_w = F(34);
    const float* proj_w = F(35);  const float* proj_b = F(36);

    constexpr size_t F512 = (size_t)B_ * L_ * D_;   // 8388608
    constexpr size_t F64  = (size_t)B_ * L_ * C_;   // 1048576
    constexpr size_t SMALL = 1024 + 16384 + 320 + 320 + 8192;
    constexpr size_t WTSN = 2 * 1024 * 1024;        // bf16 weight scratch elems
    size_t need = (5 * F512 + 2 * F64 + SMALL) * 4 + (4 * F512 + WTSN) * 2;
    if (ws_size < need) return;

    float* X      = (float*)d_ws;
    float* T1     = X + F512;
    float* T2     = T1 + F512;
    float* T3     = T2 + F512;
    float* TSUM   = T3 + F512;
    float* SEASIN = TSUM + F512;
    float* TREND  = SEASIN + F64;
    float* MEANC  = TREND + F64;
    float* G      = MEANC + 1024;
    float* TCW    = G + 16384;
    int*   DEL    = (int*)(TCW + 320);
    float* LNMEAN = (float*)(DEL + 320);
    unsigned short* AB  = (unsigned short*)(LNMEAN + 8192);
    unsigned short* EB  = AB + F512;
    unsigned short* VB  = EB + F512;
    unsigned short* HB  = VB + F512;
    unsigned short* WTS = HB + F512;
    float* OUT = (float*)d_out;

    const int M = B_ * L_;  // 16384

    auto gemm = [&](const float* A, const float* Bm, float* Cm, const float* bias,
                    int Mm, int Nn, int Kk, int flags, int shift = 0, int shiftL = 0) {
        dim3 g(Nn / GBN, Mm / GBM);
        gemm_f32<<<g, 256, 0, stream>>>(A, Bm, Cm, bias, Mm, Nn, Kk, flags, shift, shiftL);
    };
    auto mgemm = [&](const unsigned short* A, const unsigned short* Bt, float* Cf,
                     unsigned short* Cb, const float* bias, int Mm, int Nn, int Kk, int flags) {
        dim3 g(Nn / 128, Mm / 128);
        gemm_bf16<<<g, 256, 0, stream>>>(A, Bt, Cf, Cb, bias, Mm, Nn, Kk, flags);
    };
    auto tcast = [&](const float* W, unsigned short* Wt, int R, int Cc) {
        tcast_kernel<<<dim3(Cc / 32, R / 32), 256, 0, stream>>>(W, Wt, R, Cc);
    };
    auto attn = [&](const unsigned short* qin, const unsigned short* kvin,
                    const float* Wq, const float* bq, const float* Wk, const float* bk,
                    const float* Wv, const float* bvp, const float* Wo, const float* bo,
                    float* resid) {
        unsigned short* Wt0 = WTS;
        unsigned short* Wt1 = WTS + 262144;
        unsigned short* Wt2 = WTS + 524288;
        unsigned short* Wt3 = WTS + 786432;
        tcast(Wq, Wt0, 512, 512);
        tcast(Wk, Wt1, 512, 512);
        tcast(Wv, Wt2, 512, 512);
        tcast(Wo, Wt3, 512, 512);
        mgemm(qin,  Wt0, T2, nullptr, bq, M, 512, 512, 0);
        mgemm(kvin, Wt1, T3, nullptr, bk, M, 512, 512, 0);
        mgemm(kvin, Wt2, nullptr, VB, bvp, M, 512, 512, 0);
        zero_kernel<<<16384 / 256, 256, 0, stream>>>(G, 16384);
        corr_diag<<<dim3(8, 8, 16), 256, 0, stream>>>(T2, T3, G);
        topk_kernel<<<16, 256, 0, stream>>>(G, DEL, TCW);
        agg_kernel<<<(int)(F512 / 8 / 256), 256, 0, stream>>>(VB, DEL, TCW, HB);
        mgemm(HB, Wt3, resid, nullptr, bo, M, 512, 512, 1);
    };
    auto ffblock = [&](const unsigned short* xin, const float* W1, const float* W2, float* resid) {
        unsigned short* Wf1 = WTS;
        unsigned short* Wf2 = WTS + 1048576;
        tcast(W1, Wf1, 512, 2048);
        tcast(W2, Wf2, 2048, 512);
        for (int c = 0; c < 4; ++c) {
            mgemm(xin + (size_t)c * 4096 * 512, Wf1, nullptr, HB, nullptr, 4096, 2048, 512, 2);
            mgemm(HB, Wf2, resid + (size_t)c * 4096 * 512, nullptr, nullptr, 4096, 512, 2048, 1);
        }
    };

    // ---------------- prep: decomposition of x_enc, decoder inits -----------
    float* SEENC = T2;  // aliases: prep phase only
    float* TRENC = T3;
    decomp_kernel<<<(B_ * C_ * 8 + 255) / 256, 256, 0, stream>>>(x_enc, SEENC, nullptr, TRENC, B_, L_, C_, 8, 1);
    meanx_kernel<<<(B_ * C_ + 255) / 256, 256, 0, stream>>>(x_enc, MEANC);
    builddec_kernel<<<(int)(F64 / 256), 256, 0, stream>>>(TRENC, SEENC, MEANC, TREND, SEASIN);

    // ---------------- encoder ----------------------------------------------
    gemm(x_enc, enc_emb_w,               X, nullptr, M, D_, C_, 0, -1, L_);
    gemm(x_enc, enc_emb_w + 1 * C_ * D_, X, nullptr, M, D_, C_, 1,  0, L_);
    gemm(x_enc, enc_emb_w + 2 * C_ * D_, X, nullptr, M, D_, C_, 1,  1, L_);
    addpos_kernel<<<(int)(F512 / 256), 256, 0, stream>>>(X, AB);

    for (int l = 0; l < 2; ++l) {
        attn(AB, AB,
             enc_Wq + (size_t)l * D_ * D_, enc_bq + l * D_,
             enc_Wk + (size_t)l * D_ * D_, enc_bk + l * D_,
             enc_Wv + (size_t)l * D_ * D_, enc_bv + l * D_,
             enc_Wo + (size_t)l * D_ * D_, enc_bo + l * D_, X);
        decomp_kernel<<<(B_ * D_ * 8 + 255) / 256, 256, 0, stream>>>(X, T1, AB, nullptr, B_, L_, D_, 8, 0);
        ffblock(AB, enc_ff1 + (size_t)l * D_ * DFF_, enc_ff2 + (size_t)l * DFF_ * D_, T1);
        decomp_kernel<<<(B_ * D_ * 8 + 255) / 256, 256, 0, stream>>>(T1, X, AB, nullptr, B_, L_, D_, 8, 0);
    }
    lnrow_kernel<<<M, 256, 0, stream>>>(X, enc_ng, enc_nb, T1);
    colmean_kernel<<<(B_ * D_ + 255) / 256, 256, 0, stream>>>(T1, LNMEAN);
    colsub_kernel<<<(int)(F512 / 256), 256, 0, stream>>>(T1, LNMEAN, EB);

    // ---------------- decoder ----------------------------------------------
    float* XD = X;
    gemm(SEASIN, dec_emb_w,               XD, nullptr, M, D_, C_, 0, -1, L_);
    gemm(SEASIN, dec_emb_w + 1 * C_ * D_, XD, nullptr, M, D_, C_, 1,  0, L_);
    gemm(SEASIN, dec_emb_w + 2 * C_ * D_, XD, nullptr, M, D_, C_, 1,  1, L_);
    addpos_kernel<<<(int)(F512 / 256), 256, 0, stream>>>(XD, AB);

    attn(AB, AB, dsa_Wq, dsa_bq, dsa_Wk, dsa_bk, dsa_Wv, dsa_bv, dsa_Wo, dsa_bo, XD);
    decomp_kernel<<<(B_ * D_ * 8 + 255) / 256, 256, 0, stream>>>(XD, T1, AB, TSUM, B_, L_, D_, 8, 1);

    attn(AB, EB, dca_Wq, dca_bq, dca_Wk, dca_bk, dca_Wv, dca_bv, dca_Wo, dca_bo, T1);
    decomp_kernel<<<(B_ * D_ * 8 + 255) / 256, 256, 0, stream>>>(T1, XD, AB, TSUM, B_, L_, D_, 8, 2);

    ffblock(AB, dec_ff1, dec_ff2, XD);
    decomp_kernel<<<(B_ * D_ * 8 + 255) / 256, 256, 0, stream>>>(XD, T1, nullptr, TSUM, B_, L_, D_, 8, 2);

    // trend projection conv (3 taps) accumulated onto TREND
    gemm(TSUM, dec_trend_w,               TREND, nullptr, M, C_, D_, 1, -1, L_);
    gemm(TSUM, dec_trend_w + 1 * D_ * C_, TREND, nullptr, M, C_, D_, 1,  0, L_);
    gemm(TSUM, dec_trend_w + 2 * D_ * C_, TREND, nullptr, M, C_, D_, 1,  1, L_);

    // seasonal projection + final output
    float* S64 = T2;  // T2 free by now
    gemm(T1, proj_w, S64, proj_b, M, C_, D_, 0);
    final_kernel<<<(B_ * 512 * C_) / 256, 256, 0, stream>>>(TREND, S64, OUT);
}

// Round 5
// 3194.373 us; speedup vs baseline: 2.8444x; 1.1682x over previous
//
#include <hip/hip_runtime.h>
#include <math.h>

#define B_   16
#define L_   1024
#define C_   64
#define D_   512
#define DFF_ 2048
#define TOPK_ 20

constexpr int GBM = 64, GBN = 64, GBK = 16;

typedef float f4 __attribute__((ext_vector_type(4)));
typedef float f32x4 __attribute__((ext_vector_type(4)));
typedef short bf16x8 __attribute__((ext_vector_type(8)));
typedef unsigned short u16x8 __attribute__((ext_vector_type(8)));

__device__ __forceinline__ unsigned short f2bf(float f) {
    union { float f; unsigned u; } a; a.f = f;
    unsigned r = a.u + 0x7fff + ((a.u >> 16) & 1);
    return (unsigned short)(r >> 16);
}
__device__ __forceinline__ float bf2f(unsigned short h) {
    union { unsigned u; float f; } a; a.u = ((unsigned)h) << 16;
    return a.f;
}

__device__ __forceinline__ void gld16(const void* g, void* l) {
    __builtin_amdgcn_global_load_lds(
        (const __attribute__((address_space(1))) unsigned int*)g,
        (__attribute__((address_space(3))) unsigned int*)l, 16, 0, 0);
}

// ---------------------------------------------------------------------------
// bf16 MFMA GEMM: C[M,N] = op(A[M,K] @ B[K,N] + bias)
// A: bf16 [M][K]. Bt: bf16 [N][K] (pre-transposed). Outputs (any subset):
//   Cf f32 (flags&1: accumulate), Cb bf16 (= round(c)), Cl bf16 (= round(c-hi))
// flags&2: exact GELU. 1D grid with XCD-bijective swizzle; nx = N/128.
// ---------------------------------------------------------------------------
__global__ __launch_bounds__(256)
void gemm_bf16(const unsigned short* __restrict__ A, const unsigned short* __restrict__ Bt,
               float* __restrict__ Cf, unsigned short* __restrict__ Cb,
               unsigned short* __restrict__ Cl,
               const float* __restrict__ bias, int M, int N, int K, int flags, int nx)
{
    __shared__ unsigned short As[128 * 32];
    __shared__ unsigned short Bs[128 * 32];
    const int tid = threadIdx.x;
    const int wave = tid >> 6, lane = tid & 63;

    // XCD swizzle: give each XCD a contiguous chunk of M-panels (A-reuse in L2)
    int total = gridDim.x;
    int h = blockIdx.x;
    int lidx = h;
    if ((total & 7) == 0) {
        int q = total >> 3;
        lidx = (h & 7) * q + (h >> 3);
    }
    const int bm = (lidx / nx) * 128, bn = (lidx % nx) * 128;
    const int wm = (wave >> 1) << 6, wn = (wave & 1) << 6;

    const int r0 = (wave << 5) + (lane >> 2);
    const int kq = (lane & 3) << 3;
    const unsigned short* Ap0 = A + (size_t)(bm + r0) * K + kq;
    const unsigned short* Ap1 = Ap0 + (size_t)16 * K;
    const unsigned short* Bp0 = Bt + (size_t)(bn + r0) * K + kq;
    const unsigned short* Bp1 = Bp0 + (size_t)16 * K;
    unsigned short* Al0 = &As[(wave << 5) * 32];
    unsigned short* Al1 = &As[((wave << 5) + 16) * 32];
    unsigned short* Bl0 = &Bs[(wave << 5) * 32];
    unsigned short* Bl1 = &Bs[((wave << 5) + 16) * 32];

    const int la = lane & 15, h4 = lane >> 4;
    f32x4 acc[4][4] = {};

    for (int k0 = 0; k0 < K; k0 += 32) {
        gld16(Ap0 + k0, Al0);
        gld16(Ap1 + k0, Al1);
        gld16(Bp0 + k0, Bl0);
        gld16(Bp1 + k0, Bl1);
        __syncthreads();
        bf16x8 a[4], b[4];
#pragma unroll
        for (int i = 0; i < 4; ++i) {
            a[i] = *(const bf16x8*)&As[(wm + i * 16 + la) * 32 + h4 * 8];
            b[i] = *(const bf16x8*)&Bs[(wn + i * 16 + la) * 32 + h4 * 8];
        }
#pragma unroll
        for (int mi = 0; mi < 4; ++mi)
#pragma unroll
            for (int ni = 0; ni < 4; ++ni)
                acc[mi][ni] = __builtin_amdgcn_mfma_f32_16x16x32_bf16(a[mi], b[ni], acc[mi][ni], 0, 0, 0);
        __syncthreads();
    }

#pragma unroll
    for (int mi = 0; mi < 4; ++mi) {
#pragma unroll
        for (int r = 0; r < 4; ++r) {
            int m = bm + wm + mi * 16 + h4 * 4 + r;
#pragma unroll
            for (int ni = 0; ni < 4; ++ni) {
                int n = bn + wn + ni * 16 + la;
                float c = acc[mi][ni][r];
                if (bias) c += bias[n];
                if (flags & 2) c = 0.5f * c * (1.0f + erff(c * 0.70710678118654752f));
                size_t o = (size_t)m * N + n;
                if (Cf) { if (flags & 1) Cf[o] += c; else Cf[o] = c; }
                if (Cb) {
                    unsigned short hb = f2bf(c);
                    Cb[o] = hb;
                    if (Cl) Cl[o] = f2bf(c - bf2f(hb));
                }
            }
        }
    }
}

// transpose + cast: W [R][Cc] f32 -> Wt [Cc][R] bf16
__global__ __launch_bounds__(256)
void tcast_kernel(const float* __restrict__ W, unsigned short* __restrict__ Wt, int R, int Cc)
{
    __shared__ float t[32][33];
    int bx = blockIdx.x * 32, by = blockIdx.y * 32;
    int tx = threadIdx.x & 31, ty = threadIdx.x >> 5;
#pragma unroll
    for (int i = 0; i < 32; i += 8)
        t[ty + i][tx] = W[(size_t)(by + ty + i) * Cc + bx + tx];
    __syncthreads();
#pragma unroll
    for (int i = 0; i < 32; i += 8)
        Wt[(size_t)(bx + ty + i) * R + by + tx] = f2bf(t[tx][ty + i]);
}

// ---------------------------------------------------------------------------
// Generic f32 GEMM (embeddings / trend conv / proj).
// flags bit0: accumulate, bit1: GELU. shiftL>0: circular A-row remap.
// ---------------------------------------------------------------------------
__global__ __launch_bounds__(256)
void gemm_f32(const float* __restrict__ A, const float* __restrict__ Bm,
              float* __restrict__ Cm, const float* __restrict__ bias,
              int M, int N, int K, int flags, int shift, int shiftL)
{
    __shared__ float As[GBK][GBM + 4];
    __shared__ float Bs[GBK][GBN + 4];
    const int tid = threadIdx.x;
    const int bm = blockIdx.y * GBM;
    const int bn = blockIdx.x * GBN;
    const int tx = tid & 15, ty = tid >> 4;
    const int a_k = tid & 15, a_m0 = tid >> 4;
    const int b_n = tid & 63, b_k0 = tid >> 6;
    float acc[4][4] = {};
    for (int k0 = 0; k0 < K; k0 += GBK) {
#pragma unroll
        for (int r = 0; r < 4; ++r) {
            int m = bm + a_m0 + r * 16;
            int row = m;
            if (shiftL > 0) {
                int l = m & (shiftL - 1);
                int base = m - l;
                l += shift;
                if (l < 0) l += shiftL; else if (l >= shiftL) l -= shiftL;
                row = base + l;
            }
            As[a_k][a_m0 + r * 16] = A[(size_t)row * K + (k0 + a_k)];
        }
#pragma unroll
        for (int r = 0; r < 4; ++r) {
            int kk = b_k0 + r * 4;
            Bs[kk][b_n] = Bm[(size_t)(k0 + kk) * N + (bn + b_n)];
        }
        __syncthreads();
#pragma unroll
        for (int kk = 0; kk < GBK; ++kk) {
            f4 av = *(const f4*)&As[kk][ty * 4];
            f4 bv = *(const f4*)&Bs[kk][tx * 4];
#pragma unroll
            for (int i = 0; i < 4; ++i)
#pragma unroll
                for (int j = 0; j < 4; ++j)
                    acc[i][j] = fmaf(av[i], bv[j], acc[i][j]);
        }
        __syncthreads();
    }
#pragma unroll
    for (int i = 0; i < 4; ++i) {
        int m = bm + ty * 4 + i;
#pragma unroll
        for (int j = 0; j < 4; ++j) {
            int n = bn + tx * 4 + j;
            float c = acc[i][j];
            if (bias) c += bias[n];
            if (flags & 2) c = 0.5f * c * (1.0f + erff(c * 0.70710678118654752f));
            size_t o = (size_t)m * N + n;
            if (flags & 1) Cm[o] += c; else Cm[o] = c;
        }
    }
}

// ---------------------------------------------------------------------------
// Autocorrelation scores v3: bf16x3 MFMA (hi/lo split, error ~1e-7 rel).
// 128x128 tile, 4 waves (2x2), 4x4 frags each. acc = hq*hk + hq*lk + lq*hk.
// Diag reduction: frags with equal (mi-ni) share bins -> 28 atomics/thread.
// ---------------------------------------------------------------------------
__global__ __launch_bounds__(256)
void corr_mfma(const unsigned short* __restrict__ Qh, const unsigned short* __restrict__ Ql,
               const unsigned short* __restrict__ Kh, const unsigned short* __restrict__ Kl,
               float* __restrict__ G)
{
    __shared__ unsigned short Qhs[128 * 32], Qls[128 * 32], Khs[128 * 32], Kls[128 * 32];
    __shared__ float diagw[4][256];
    const int tid = threadIdx.x;
    const int wave = tid >> 6, lane = tid & 63;
    const int b = blockIdx.z;
    const int bt = blockIdx.y * 128, bs = blockIdx.x * 128;
    const int wm = (wave >> 1) << 6, wn = (wave & 1) << 6;
    const size_t boff = (size_t)b << 19;

    const int r0 = (wave << 5) + (lane >> 2);
    const int kq = (lane & 3) << 3;
    const size_t g0 = boff + (size_t)(bt + r0) * 512 + kq;
    const size_t g1 = g0 + (size_t)16 * 512;
    const size_t p0 = boff + (size_t)(bs + r0) * 512 + kq;
    const size_t p1 = p0 + (size_t)16 * 512;
    unsigned short* qh0 = &Qhs[(wave << 5) * 32]; unsigned short* qh1 = &Qhs[((wave << 5) + 16) * 32];
    unsigned short* ql0 = &Qls[(wave << 5) * 32]; unsigned short* ql1 = &Qls[((wave << 5) + 16) * 32];
    unsigned short* kh0 = &Khs[(wave << 5) * 32]; unsigned short* kh1 = &Khs[((wave << 5) + 16) * 32];
    unsigned short* kl0 = &Kls[(wave << 5) * 32]; unsigned short* kl1 = &Kls[((wave << 5) + 16) * 32];

    float* dz = &diagw[0][0];
    dz[tid] = 0.f; dz[tid + 256] = 0.f; dz[tid + 512] = 0.f; dz[tid + 768] = 0.f;

    const int la = lane & 15, h4 = lane >> 4;
    f32x4 acc[4][4] = {};

    for (int k0 = 0; k0 < 512; k0 += 32) {
        gld16(Qh + g0 + k0, qh0); gld16(Qh + g1 + k0, qh1);
        gld16(Ql + g0 + k0, ql0); gld16(Ql + g1 + k0, ql1);
        gld16(Kh + p0 + k0, kh0); gld16(Kh + p1 + k0, kh1);
        gld16(Kl + p0 + k0, kl0); gld16(Kl + p1 + k0, kl1);
        __syncthreads();
        bf16x8 ah[4], al[4], bh[4], bl[4];
#pragma unroll
        for (int i = 0; i < 4; ++i) {
            int ro = (wm + i * 16 + la) * 32 + h4 * 8;
            int co = (wn + i * 16 + la) * 32 + h4 * 8;
            ah[i] = *(const bf16x8*)&Qhs[ro];
            al[i] = *(const bf16x8*)&Qls[ro];
            bh[i] = *(const bf16x8*)&Khs[co];
            bl[i] = *(const bf16x8*)&Kls[co];
        }
#pragma unroll
        for (int mi = 0; mi < 4; ++mi)
#pragma unroll
            for (int ni = 0; ni < 4; ++ni) {
                acc[mi][ni] = __builtin_amdgcn_mfma_f32_16x16x32_bf16(ah[mi], bh[ni], acc[mi][ni], 0, 0, 0);
                acc[mi][ni] = __builtin_amdgcn_mfma_f32_16x16x32_bf16(ah[mi], bl[ni], acc[mi][ni], 0, 0, 0);
                acc[mi][ni] = __builtin_amdgcn_mfma_f32_16x16x32_bf16(al[mi], bh[ni], acc[mi][ni], 0, 0, 0);
            }
        __syncthreads();
    }

    // register pre-reduction: frags with equal d = mi-ni share diag bins
    float rbin[7][4] = {};
#pragma unroll
    for (int mi = 0; mi < 4; ++mi)
#pragma unroll
        for (int ni = 0; ni < 4; ++ni)
#pragma unroll
            for (int r = 0; r < 4; ++r)
                rbin[mi - ni + 3][r] += acc[mi][ni][r];

    const int base = (wm - wn) + 4 * h4 - la + 127;
#pragma unroll
    for (int d = 0; d < 7; ++d)
#pragma unroll
        for (int r = 0; r < 4; ++r)
            atomicAdd(&diagw[wave][base + 16 * (d - 3) + r], rbin[d][r]);
    __syncthreads();
    if (tid < 255) {
        float s = diagw[0][tid] + diagw[1][tid] + diagw[2][tid] + diagw[3][tid];
        int n = (bt - bs + tid - 127) & 1023;
        atomicAdd(&G[(b << 10) + n], s);
    }
}

// ---------------------------------------------------------------------------
// Per-batch top-20 + softmax, parallel argmax (tie -> lowest index).
// ---------------------------------------------------------------------------
__global__ __launch_bounds__(256)
void topk_kernel(const float* __restrict__ G, int* __restrict__ delay,
                 float* __restrict__ tc)
{
    __shared__ float vals[1024];
    __shared__ float pw[4];
    __shared__ int   pwi[4];
    __shared__ float wsel[TOPK_];
    __shared__ int   isel[TOPK_];
    const int b = blockIdx.x, tid = threadIdx.x;
    const int lane = tid & 63, wid = tid >> 6;
    for (int i = tid; i < 1024; i += 256) vals[i] = G[(b << 10) + i] * (1.0f / 512.0f);
    __syncthreads();
    for (int it = 0; it < TOPK_; ++it) {
        float bv = -INFINITY; int bi = 0;
#pragma unroll
        for (int u = 0; u < 4; ++u) {
            int i = tid * 4 + u;
            float v = vals[i];
            if (v > bv) { bv = v; bi = i; }
        }
#pragma unroll
        for (int o = 32; o > 0; o >>= 1) {
            float ov = __shfl_xor(bv, o, 64);
            int   oi = __shfl_xor(bi, o, 64);
            if (ov > bv || (ov == bv && oi < bi)) { bv = ov; bi = oi; }
        }
        if (lane == 0) { pw[wid] = bv; pwi[wid] = bi; }
        __syncthreads();
        if (tid == 0) {
            float m = pw[0]; int mi = pwi[0];
#pragma unroll
            for (int t = 1; t < 4; ++t)
                if (pw[t] > m || (pw[t] == m && pwi[t] < mi)) { m = pw[t]; mi = pwi[t]; }
            wsel[it] = m; isel[it] = mi;
            vals[mi] = -INFINITY;
        }
        __syncthreads();
    }
    if (tid == 0) {
        float m = wsel[0];
#pragma unroll
        for (int i = 1; i < TOPK_; ++i) m = fmaxf(m, wsel[i]);
        float e[TOPK_], s = 0.f;
#pragma unroll
        for (int i = 0; i < TOPK_; ++i) { e[i] = expf(wsel[i] - m); s += e[i]; }
        float inv = 1.0f / s;
#pragma unroll
        for (int i = 0; i < TOPK_; ++i) {
            tc[b * TOPK_ + i] = e[i] * inv;
            delay[b * TOPK_ + i] = isel[i];
        }
    }
}

// out[b,l,d] = sum_i tc[b,i] * V[b,(l+delay)%1024,d], bf16 in/out, 8-wide
__global__ void agg_kernel(const unsigned short* __restrict__ V, const int* __restrict__ delay,
                           const float* __restrict__ tc, unsigned short* __restrict__ out)
{
    int idx = (blockIdx.x * blockDim.x + threadIdx.x) * 8;
    int d = idx & 511;
    int l = (idx >> 9) & 1023;
    int b = idx >> 19;
    const unsigned short* Vb = V + ((size_t)b << 19);
    float s[8] = {};
#pragma unroll
    for (int i = 0; i < TOPK_; ++i) {
        int row = (l + delay[b * TOPK_ + i]) & 1023;
        float w = tc[b * TOPK_ + i];
        u16x8 v = *(const u16x8*)&Vb[((size_t)row << 9) + d];
#pragma unroll
        for (int j = 0; j < 8; ++j)
            s[j] = fmaf(w, bf2f(v[j]), s[j]);
    }
    u16x8 o;
#pragma unroll
    for (int j = 0; j < 8; ++j) o[j] = f2bf(s[j]);
    *(u16x8*)&out[idx] = o;
}

// ---------------------------------------------------------------------------
// series_decomp with optional bf16 dual-out of the seasonal part.
// ---------------------------------------------------------------------------
__global__ void decomp_kernel(const float* __restrict__ x, float* __restrict__ seas,
                              unsigned short* __restrict__ seasb,
                              float* __restrict__ trend, int Bn, int Ln, int Ch,
                              int nseg, int tmode)
{
    int idx = blockIdx.x * blockDim.x + threadIdx.x;
    int total = Bn * Ch * nseg;
    if (idx >= total) return;
    int ch = idx % Ch;
    int rest = idx / Ch;
    int seg = rest % nseg;
    int b = rest / nseg;
    int segL = Ln / nseg;
    int l0 = seg * segL;
    const float* xp = x + (size_t)b * Ln * Ch + ch;
    float* sp = seas + (size_t)b * Ln * Ch + ch;
    unsigned short* bp = seasb ? seasb + (size_t)b * Ln * Ch + ch : nullptr;
    float* tp = trend ? trend + (size_t)b * Ln * Ch + ch : nullptr;
    float s = 0.f;
    for (int j = -12; j <= 12; ++j) {
        int t = l0 + j;
        t = t < 0 ? 0 : (t > Ln - 1 ? Ln - 1 : t);
        s += xp[(size_t)t * Ch];
    }
    for (int l = l0; l < l0 + segL; ++l) {
        float mm = s * (1.0f / 25.0f);
        float v = xp[(size_t)l * Ch] - mm;
        sp[(size_t)l * Ch] = v;
        if (bp) bp[(size_t)l * Ch] = f2bf(v);
        if (tmode == 1) tp[(size_t)l * Ch] = mm;
        else if (tmode == 2) tp[(size_t)l * Ch] += mm;
        int ta = l + 13; if (ta > Ln - 1) ta = Ln - 1;
        int ts = l - 12; if (ts < 0) ts = 0;
        s += xp[(size_t)ta * Ch] - xp[(size_t)ts * Ch];
    }
}

// x += pos emb (f32 in place) and write bf16 copy
__global__ void addpos_kernel(float* __restrict__ x, unsigned short* __restrict__ xb)
{
    int idx = blockIdx.x * blockDim.x + threadIdx.x;
    int d = idx & 511;
    int l = (idx >> 9) & 1023;
    int i2 = d & ~1;
    float div = expf(-(float)i2 * 0.017988946039015984f);
    float ang = (float)l * div;
    float v = x[idx] + ((d & 1) ? cosf(ang) : sinf(ang));
    x[idx] = v;
    xb[idx] = f2bf(v);
}

__global__ __launch_bounds__(256)
void lnrow_kernel(const float* __restrict__ x, const float* __restrict__ g,
                  const float* __restrict__ bv, float* __restrict__ out)
{
    __shared__ float sh1[4], sh2[4];
    int row = blockIdx.x, tid = threadIdx.x;
    const float* xr = x + ((size_t)row << 9);
    float v0 = xr[tid], v1 = xr[tid + 256];
    float s = v0 + v1, q = v0 * v0 + v1 * v1;
#pragma unroll
    for (int o = 32; o > 0; o >>= 1) {
        s += __shfl_down(s, o, 64);
        q += __shfl_down(q, o, 64);
    }
    int wid = tid >> 6;
    if ((tid & 63) == 0) { sh1[wid] = s; sh2[wid] = q; }
    __syncthreads();
    if (tid == 0) {
        sh1[0] = sh1[0] + sh1[1] + sh1[2] + sh1[3];
        sh2[0] = sh2[0] + sh2[1] + sh2[2] + sh2[3];
    }
    __syncthreads();
    float mu = sh1[0] * (1.0f / 512.0f);
    float var = sh2[0] * (1.0f / 512.0f) - mu * mu;
    float inv = rsqrtf(var + 1e-5f);
    out[((size_t)row << 9) + tid] = (v0 - mu) * inv * g[tid] + bv[tid];
    out[((size_t)row << 9) + tid + 256] = (v1 - mu) * inv * g[tid + 256] + bv[tid + 256];
}

__global__ void colmean_kernel(const float* __restrict__ x, float* __restrict__ m)
{
    int idx = blockIdx.x * blockDim.x + threadIdx.x;
    if (idx >= B_ * D_) return;
    int b = idx >> 9, d = idx & 511;
    const float* xp = x + ((size_t)b << 19) + d;
    float s = 0.f;
    for (int l = 0; l < L_; ++l) s += xp[(size_t)l << 9];
    m[idx] = s * (1.0f / 1024.0f);
}

// out_bf16 = x - colmean (encoder output, bf16 only)
__global__ void colsub_kernel(const float* __restrict__ x, const float* __restrict__ m,
                              unsigned short* __restrict__ out)
{
    int idx = blockIdx.x * blockDim.x + threadIdx.x;
    int d = idx & 511;
    int b = idx >> 19;
    out[idx] = f2bf(x[idx] - m[(b << 9) + d]);
}

__global__ void meanx_kernel(const float* __restrict__ x, float* __restrict__ m)
{
    int idx = blockIdx.x * blockDim.x + threadIdx.x;
    if (idx >= B_ * C_) return;
    int b = idx >> 6, c = idx & 63;
    const float* xp = x + (size_t)b * L_ * C_ + c;
    float s = 0.f;
    for (int l = 0; l < L_; ++l) s += xp[(size_t)l << 6];
    m[idx] = s * (1.0f / 1024.0f);
}

__global__ void builddec_kernel(const float* __restrict__ trenc, const float* __restrict__ seenc,
                                const float* __restrict__ meanc,
                                float* __restrict__ trend, float* __restrict__ seasin)
{
    int idx = blockIdx.x * blockDim.x + threadIdx.x;
    int c = idx & 63;
    int l = (idx >> 6) & 1023;
    int b = idx >> 16;
    if (l < 512) {
        int src = (b << 16) + ((512 + l) << 6) + c;
        trend[idx] = trenc[src];
        seasin[idx] = seenc[src];
    } else {
        trend[idx] = meanc[(b << 6) + c];
        seasin[idx] = 0.f;
    }
}

__global__ void final_kernel(const float* __restrict__ trend, const float* __restrict__ s64,
                             float* __restrict__ out)
{
    int idx = blockIdx.x * blockDim.x + threadIdx.x;
    int c = idx & 63;
    int l = (idx >> 6) & 511;
    int b = idx >> 15;
    int src = (b << 16) + ((512 + l) << 6) + c;
    out[idx] = trend[src] + s64[src];
}

__global__ void zero_kernel(float* __restrict__ p, int n)
{
    int idx = blockIdx.x * blockDim.x + threadIdx.x;
    if (idx < n) p[idx] = 0.f;
}

// ---------------------------------------------------------------------------
extern "C" void kernel_launch(void* const* d_in, const int* in_sizes, int n_in,
                              void* d_out, int out_size, void* d_ws, size_t ws_size,
                              hipStream_t stream)
{
    auto F = [&](int i) { return (const float*)d_in[i]; };
    const float* x_enc     = F(0);
    const float* enc_emb_w = F(2);
    const float* dec_emb_w = F(3);
    const float* enc_Wq = F(4);  const float* enc_bq = F(5);
    const float* dsa_Wq = F(6);  const float* dsa_bq = F(7);
    const float* dca_Wq = F(8);  const float* dca_bq = F(9);
    const float* enc_Wk = F(10); const float* enc_bk = F(11);
    const float* dsa_Wk = F(12); const float* dsa_bk = F(13);
    const float* dca_Wk = F(14); const float* dca_bk = F(15);
    const float* enc_Wv = F(16); const float* enc_bv = F(17);
    const float* dsa_Wv = F(18); const float* dsa_bv = F(19);
    const float* dca_Wv = F(20); const float* dca_bv = F(21);
    const float* enc_Wo = F(22); const float* enc_bo = F(23);
    const float* dsa_Wo = F(24); const float* dsa_bo = F(25);
    const float* dca_Wo = F(26); const float* dca_bo = F(27);
    const float* enc_ff1 = F(28); const float* enc_ff2 = F(29);
    const float* enc_ng = F(30);  const float* enc_nb = F(31);
    const float* dec_ff1 = F(32); const float* dec_ff2 = F(33);
    const float* dec_trend_w = F(34);
    const float* proj_w = F(35);  const float* proj_b = F(36);

    constexpr size_t F512 = (size_t)B_ * L_ * D_;   // 8388608
    constexpr size_t F64  = (size_t)B_ * L_ * C_;   // 1048576
    constexpr size_t SMALL = 1024 + 16384 + 320 + 320 + 8192;
    constexpr size_t WTSN = 2 * 1024 * 1024;        // bf16 weight scratch elems
    size_t need = (3 * F512 + 2 * F64 + SMALL) * 4 + (8 * F512 + WTSN) * 2;
    if (ws_size < need) return;

    float* X      = (float*)d_ws;
    float* T1     = X + F512;
    float* TSUM   = T1 + F512;
    float* SEASIN = TSUM + F512;
    float* TREND  = SEASIN + F64;
    float* MEANC  = TREND + F64;
    float* G      = MEANC + 1024;
    float* TCW    = G + 16384;
    int*   DEL    = (int*)(TCW + 320);
    float* LNMEAN = (float*)(DEL + 320);
    unsigned short* AB  = (unsigned short*)(LNMEAN + 8192);
    unsigned short* EB  = AB + F512;
    unsigned short* VB  = EB + F512;
    unsigned short* HB  = VB + F512;
    unsigned short* QHI = HB + F512;
    unsigned short* QLO = QHI + F512;
    unsigned short* KHI = QLO + F512;
    unsigned short* KLO = KHI + F512;
    unsigned short* WTS = KLO + F512;
    float* OUT = (float*)d_out;

    const int M = B_ * L_;  // 16384

    auto gemm = [&](const float* A, const float* Bm, float* Cm, const float* bias,
                    int Mm, int Nn, int Kk, int flags, int shift = 0, int shiftL = 0) {
        dim3 g(Nn / GBN, Mm / GBM);
        gemm_f32<<<g, 256, 0, stream>>>(A, Bm, Cm, bias, Mm, Nn, Kk, flags, shift, shiftL);
    };
    auto mgemm = [&](const unsigned short* A, const unsigned short* Bt, float* Cf,
                     unsigned short* Cb, unsigned short* Cl, const float* bias,
                     int Mm, int Nn, int Kk, int flags) {
        int nx = Nn / 128;
        int total = nx * (Mm / 128);
        gemm_bf16<<<total, 256, 0, stream>>>(A, Bt, Cf, Cb, Cl, bias, Mm, Nn, Kk, flags, nx);
    };
    auto tcast = [&](const float* W, unsigned short* Wt, int R, int Cc) {
        tcast_kernel<<<dim3(Cc / 32, R / 32), 256, 0, stream>>>(W, Wt, R, Cc);
    };
    auto attn = [&](const unsigned short* qin, const unsigned short* kvin,
                    const float* Wq, const float* bq, const float* Wk, const float* bk,
                    const float* Wv, const float* bvp, const float* Wo, const float* bo,
                    float* resid) {
        unsigned short* Wt0 = WTS;
        unsigned short* Wt1 = WTS + 262144;
        unsigned short* Wt2 = WTS + 524288;
        unsigned short* Wt3 = WTS + 786432;
        tcast(Wq, Wt0, 512, 512);
        tcast(Wk, Wt1, 512, 512);
        tcast(Wv, Wt2, 512, 512);
        tcast(Wo, Wt3, 512, 512);
        mgemm(qin,  Wt0, nullptr, QHI, QLO, bq, M, 512, 512, 0);
        mgemm(kvin, Wt1, nullptr, KHI, KLO, bk, M, 512, 512, 0);
        mgemm(kvin, Wt2, nullptr, VB, nullptr, bvp, M, 512, 512, 0);
        zero_kernel<<<16384 / 256, 256, 0, stream>>>(G, 16384);
        corr_mfma<<<dim3(8, 8, 16), 256, 0, stream>>>(QHI, QLO, KHI, KLO, G);
        topk_kernel<<<16, 256, 0, stream>>>(G, DEL, TCW);
        agg_kernel<<<(int)(F512 / 8 / 256), 256, 0, stream>>>(VB, DEL, TCW, HB);
        mgemm(HB, Wt3, resid, nullptr, nullptr, bo, M, 512, 512, 1);
    };
    auto ffblock = [&](const unsigned short* xin, const float* W1, const float* W2, float* resid) {
        unsigned short* Wf1 = WTS;
        unsigned short* Wf2 = WTS + 1048576;
        tcast(W1, Wf1, 512, 2048);
        tcast(W2, Wf2, 2048, 512);
        for (int c = 0; c < 4; ++c) {
            mgemm(xin + (size_t)c * 4096 * 512, Wf1, nullptr, HB, nullptr, nullptr, 4096, 2048, 512, 2);
            mgemm(HB, Wf2, resid + (size_t)c * 4096 * 512, nullptr, nullptr, nullptr, 4096, 512, 2048, 1);
        }
    };

    // ---------------- prep: decomposition of x_enc, decoder inits -----------
    float* SEENC = (float*)QHI;   // aliases: prep phase only
    float* TRENC = SEENC + F64;
    decomp_kernel<<<(B_ * C_ * 8 + 255) / 256, 256, 0, stream>>>(x_enc, SEENC, nullptr, TRENC, B_, L_, C_, 8, 1);
    meanx_kernel<<<(B_ * C_ + 255) / 256, 256, 0, stream>>>(x_enc, MEANC);
    builddec_kernel<<<(int)(F64 / 256), 256, 0, stream>>>(TRENC, SEENC, MEANC, TREND, SEASIN);

    // ---------------- encoder ----------------------------------------------
    gemm(x_enc, enc_emb_w,               X, nullptr, M, D_, C_, 0, -1, L_);
    gemm(x_enc, enc_emb_w + 1 * C_ * D_, X, nullptr, M, D_, C_, 1,  0, L_);
    gemm(x_enc, enc_emb_w + 2 * C_ * D_, X, nullptr, M, D_, C_, 1,  1, L_);
    addpos_kernel<<<(int)(F512 / 256), 256, 0, stream>>>(X, AB);

    for (int l = 0; l < 2; ++l) {
        attn(AB, AB,
             enc_Wq + (size_t)l * D_ * D_, enc_bq + l * D_,
             enc_Wk + (size_t)l * D_ * D_, enc_bk + l * D_,
             enc_Wv + (size_t)l * D_ * D_, enc_bv + l * D_,
             enc_Wo + (size_t)l * D_ * D_, enc_bo + l * D_, X);
        decomp_kernel<<<(B_ * D_ * 8 + 255) / 256, 256, 0, stream>>>(X, T1, AB, nullptr, B_, L_, D_, 8, 0);
        ffblock(AB, enc_ff1 + (size_t)l * D_ * DFF_, enc_ff2 + (size_t)l * DFF_ * D_, T1);
        decomp_kernel<<<(B_ * D_ * 8 + 255) / 256, 256, 0, stream>>>(T1, X, AB, nullptr, B_, L_, D_, 8, 0);
    }
    lnrow_kernel<<<M, 256, 0, stream>>>(X, enc_ng, enc_nb, T1);
    colmean_kernel<<<(B_ * D_ + 255) / 256, 256, 0, stream>>>(T1, LNMEAN);
    colsub_kernel<<<(int)(F512 / 256), 256, 0, stream>>>(T1, LNMEAN, EB);

    // ---------------- decoder ----------------------------------------------
    float* XD = X;
    gemm(SEASIN, dec_emb_w,               XD, nullptr, M, D_, C_, 0, -1, L_);
    gemm(SEASIN, dec_emb_w + 1 * C_ * D_, XD, nullptr, M, D_, C_, 1,  0, L_);
    gemm(SEASIN, dec_emb_w + 2 * C_ * D_, XD, nullptr, M, D_, C_, 1,  1, L_);
    addpos_kernel<<<(int)(F512 / 256), 256, 0, stream>>>(XD, AB);

    attn(AB, AB, dsa_Wq, dsa_bq, dsa_Wk, dsa_bk, dsa_Wv, dsa_bv, dsa_Wo, dsa_bo, XD);
    decomp_kernel<<<(B_ * D_ * 8 + 255) / 256, 256, 0, stream>>>(XD, T1, AB, TSUM, B_, L_, D_, 8, 1);

    attn(AB, EB, dca_Wq, dca_bq, dca_Wk, dca_bk, dca_Wv, dca_bv, dca_Wo, dca_bo, T1);
    decomp_kernel<<<(B_ * D_ * 8 + 255) / 256, 256, 0, stream>>>(T1, XD, AB, TSUM, B_, L_, D_, 8, 2);

    ffblock(AB, dec_ff1, dec_ff2, XD);
    decomp_kernel<<<(B_ * D_ * 8 + 255) / 256, 256, 0, stream>>>(XD, T1, nullptr, TSUM, B_, L_, D_, 8, 2);

    // trend projection conv (3 taps) accumulated onto TREND
    gemm(TSUM, dec_trend_w,               TREND, nullptr, M, C_, D_, 1, -1, L_);
    gemm(TSUM, dec_trend_w + 1 * D_ * C_, TREND, nullptr, M, C_, D_, 1,  0, L_);
    gemm(TSUM, dec_trend_w + 2 * D_ * C_, TREND, nullptr, M, C_, D_, 1,  1, L_);

    // seasonal projection + final output
    float* S64 = (float*)QHI;  // free by now
    gemm(T1, proj_w, S64, proj_b, M, C_, D_, 0);
    final_kernel<<<(B_ * 512 * C_) / 256, 256, 0, stream>>>(TREND, S64, OUT);
}

// Round 6
// 2748.983 us; speedup vs baseline: 3.3052x; 1.1620x over previous
//
#include <hip/hip_runtime.h>
#include <math.h>

#define B_   16
#define L_   1024
#define C_   64
#define D_   512
#define DFF_ 2048
#define TOPK_ 20

constexpr int GBM = 64, GBN = 64, GBK = 16;

typedef float f4 __attribute__((ext_vector_type(4)));
typedef float f32x4 __attribute__((ext_vector_type(4)));
typedef short bf16x8 __attribute__((ext_vector_type(8)));
typedef unsigned short u16x8 __attribute__((ext_vector_type(8)));

__device__ __forceinline__ unsigned short f2bf(float f) {
    union { float f; unsigned u; } a; a.f = f;
    unsigned r = a.u + 0x7fff + ((a.u >> 16) & 1);
    return (unsigned short)(r >> 16);
}
__device__ __forceinline__ float bf2f(unsigned short h) {
    union { unsigned u; float f; } a; a.u = ((unsigned)h) << 16;
    return a.f;
}

__device__ __forceinline__ void gld16(const void* g, void* l) {
    __builtin_amdgcn_global_load_lds(
        (const __attribute__((address_space(1))) unsigned int*)g,
        (__attribute__((address_space(3))) unsigned int*)l, 16, 0, 0);
}

// ---------------------------------------------------------------------------
// bf16 MFMA GEMM: C[M,N] = op(A[M,K] @ B[K,N] + bias)
// A: bf16 [M][K]. Bt: bf16 [N][K] (pre-transposed). Outputs (any subset):
//   Cf f32 (flags&1: accumulate), Cb bf16 (= round(c)), Cl bf16 (= round(c-hi))
// flags&2: exact GELU. 1D grid with XCD-bijective swizzle; nx = N/128.
// ---------------------------------------------------------------------------
__global__ __launch_bounds__(256)
void gemm_bf16(const unsigned short* __restrict__ A, const unsigned short* __restrict__ Bt,
               float* __restrict__ Cf, unsigned short* __restrict__ Cb,
               unsigned short* __restrict__ Cl,
               const float* __restrict__ bias, int M, int N, int K, int flags, int nx)
{
    __shared__ unsigned short As[128 * 32];
    __shared__ unsigned short Bs[128 * 32];
    const int tid = threadIdx.x;
    const int wave = tid >> 6, lane = tid & 63;

    // XCD swizzle: give each XCD a contiguous chunk of M-panels (A-reuse in L2)
    int total = gridDim.x;
    int h = blockIdx.x;
    int lidx = h;
    if ((total & 7) == 0) {
        int q = total >> 3;
        lidx = (h & 7) * q + (h >> 3);
    }
    const int bm = (lidx / nx) * 128, bn = (lidx % nx) * 128;
    const int wm = (wave >> 1) << 6, wn = (wave & 1) << 6;

    const int r0 = (wave << 5) + (lane >> 2);
    const int kq = (lane & 3) << 3;
    const unsigned short* Ap0 = A + (size_t)(bm + r0) * K + kq;
    const unsigned short* Ap1 = Ap0 + (size_t)16 * K;
    const unsigned short* Bp0 = Bt + (size_t)(bn + r0) * K + kq;
    const unsigned short* Bp1 = Bp0 + (size_t)16 * K;
    unsigned short* Al0 = &As[(wave << 5) * 32];
    unsigned short* Al1 = &As[((wave << 5) + 16) * 32];
    unsigned short* Bl0 = &Bs[(wave << 5) * 32];
    unsigned short* Bl1 = &Bs[((wave << 5) + 16) * 32];

    const int la = lane & 15, h4 = lane >> 4;
    f32x4 acc[4][4] = {};

    for (int k0 = 0; k0 < K; k0 += 32) {
        gld16(Ap0 + k0, Al0);
        gld16(Ap1 + k0, Al1);
        gld16(Bp0 + k0, Bl0);
        gld16(Bp1 + k0, Bl1);
        __syncthreads();
        bf16x8 a[4], b[4];
#pragma unroll
        for (int i = 0; i < 4; ++i) {
            a[i] = *(const bf16x8*)&As[(wm + i * 16 + la) * 32 + h4 * 8];
            b[i] = *(const bf16x8*)&Bs[(wn + i * 16 + la) * 32 + h4 * 8];
        }
#pragma unroll
        for (int mi = 0; mi < 4; ++mi)
#pragma unroll
            for (int ni = 0; ni < 4; ++ni)
                acc[mi][ni] = __builtin_amdgcn_mfma_f32_16x16x32_bf16(a[mi], b[ni], acc[mi][ni], 0, 0, 0);
        __syncthreads();
    }

#pragma unroll
    for (int mi = 0; mi < 4; ++mi) {
#pragma unroll
        for (int r = 0; r < 4; ++r) {
            int m = bm + wm + mi * 16 + h4 * 4 + r;
#pragma unroll
            for (int ni = 0; ni < 4; ++ni) {
                int n = bn + wn + ni * 16 + la;
                float c = acc[mi][ni][r];
                if (bias) c += bias[n];
                if (flags & 2) c = 0.5f * c * (1.0f + erff(c * 0.70710678118654752f));
                size_t o = (size_t)m * N + n;
                if (Cf) { if (flags & 1) Cf[o] += c; else Cf[o] = c; }
                if (Cb) {
                    unsigned short hb = f2bf(c);
                    Cb[o] = hb;
                    if (Cl) Cl[o] = f2bf(c - bf2f(hb));
                }
            }
        }
    }
}

// transpose + cast: W [R][Cc] f32 -> Wt [Cc][R] bf16
__global__ __launch_bounds__(256)
void tcast_kernel(const float* __restrict__ W, unsigned short* __restrict__ Wt, int R, int Cc)
{
    __shared__ float t[32][33];
    int bx = blockIdx.x * 32, by = blockIdx.y * 32;
    int tx = threadIdx.x & 31, ty = threadIdx.x >> 5;
#pragma unroll
    for (int i = 0; i < 32; i += 8)
        t[ty + i][tx] = W[(size_t)(by + ty + i) * Cc + bx + tx];
    __syncthreads();
#pragma unroll
    for (int i = 0; i < 32; i += 8)
        Wt[(size_t)(bx + ty + i) * R + by + tx] = f2bf(t[tx][ty + i]);
}

// ---------------------------------------------------------------------------
// Fused tap-conv f32 GEMM: C[M,N] = [C +] sum_tap A(rowshift tap-1)[M,K] @ W[tap][K,N]
// taps==3: circular shift -1,0,+1 within 1024-row groups; taps==1: plain.
// flags: 1 accumulate, 4 add sinusoidal pos-emb. Cb: optional bf16 dual-out.
// Register accumulation across taps == old multi-pass store/accumulate order.
// ---------------------------------------------------------------------------
__global__ __launch_bounds__(256)
void conv_gemm_f32(const float* __restrict__ A, const float* __restrict__ Wt,
                   float* __restrict__ Cm, unsigned short* __restrict__ Cb,
                   const float* __restrict__ bias,
                   int M, int N, int K, int flags, int taps)
{
    __shared__ float As[GBK][GBM + 4];
    __shared__ float Bs[GBK][GBN + 4];
    const int tid = threadIdx.x;
    const int bm = blockIdx.y * GBM;
    const int bn = blockIdx.x * GBN;
    const int tx = tid & 15, ty = tid >> 4;
    const int a_k = tid & 15, a_m0 = tid >> 4;
    const int b_n = tid & 63, b_k0 = tid >> 6;
    float acc[4][4] = {};
    for (int tap = 0; tap < taps; ++tap) {
        const int shift = (taps == 3) ? (tap - 1) : 0;
        const float* Bm = Wt + (size_t)tap * K * N;
        for (int k0 = 0; k0 < K; k0 += GBK) {
#pragma unroll
            for (int r = 0; r < 4; ++r) {
                int m = bm + a_m0 + r * 16;
                int l = m & 1023;
                int base = m - l;
                l += shift;
                if (l < 0) l += 1024; else if (l >= 1024) l -= 1024;
                As[a_k][a_m0 + r * 16] = A[(size_t)(base + l) * K + (k0 + a_k)];
            }
#pragma unroll
            for (int r = 0; r < 4; ++r) {
                int kk = b_k0 + r * 4;
                Bs[kk][b_n] = Bm[(size_t)(k0 + kk) * N + (bn + b_n)];
            }
            __syncthreads();
#pragma unroll
            for (int kk = 0; kk < GBK; ++kk) {
                f4 av = *(const f4*)&As[kk][ty * 4];
                f4 bv = *(const f4*)&Bs[kk][tx * 4];
#pragma unroll
                for (int i = 0; i < 4; ++i)
#pragma unroll
                    for (int j = 0; j < 4; ++j)
                        acc[i][j] = fmaf(av[i], bv[j], acc[i][j]);
            }
            __syncthreads();
        }
    }
#pragma unroll
    for (int i = 0; i < 4; ++i) {
        int m = bm + ty * 4 + i;
#pragma unroll
        for (int j = 0; j < 4; ++j) {
            int n = bn + tx * 4 + j;
            float c = acc[i][j];
            if (bias) c += bias[n];
            if (flags & 4) {
                int l = m & 1023;
                int i2 = n & ~1;
                float div = expf(-(float)i2 * 0.017988946039015984f);
                float ang = (float)l * div;
                c += (n & 1) ? cosf(ang) : sinf(ang);
            }
            size_t o = (size_t)m * N + n;
            if (flags & 1) Cm[o] += c; else Cm[o] = c;
            if (Cb) Cb[o] = f2bf(c);
        }
    }
}

// ---------------------------------------------------------------------------
// Autocorrelation scores v3: bf16x3 MFMA (hi/lo split, error ~1e-7 rel).
// ---------------------------------------------------------------------------
__global__ __launch_bounds__(256)
void corr_mfma(const unsigned short* __restrict__ Qh, const unsigned short* __restrict__ Ql,
               const unsigned short* __restrict__ Kh, const unsigned short* __restrict__ Kl,
               float* __restrict__ G)
{
    __shared__ unsigned short Qhs[128 * 32], Qls[128 * 32], Khs[128 * 32], Kls[128 * 32];
    __shared__ float diagw[4][256];
    const int tid = threadIdx.x;
    const int wave = tid >> 6, lane = tid & 63;
    const int b = blockIdx.z;
    const int bt = blockIdx.y * 128, bs = blockIdx.x * 128;
    const int wm = (wave >> 1) << 6, wn = (wave & 1) << 6;
    const size_t boff = (size_t)b << 19;

    const int r0 = (wave << 5) + (lane >> 2);
    const int kq = (lane & 3) << 3;
    const size_t g0 = boff + (size_t)(bt + r0) * 512 + kq;
    const size_t g1 = g0 + (size_t)16 * 512;
    const size_t p0 = boff + (size_t)(bs + r0) * 512 + kq;
    const size_t p1 = p0 + (size_t)16 * 512;
    unsigned short* qh0 = &Qhs[(wave << 5) * 32]; unsigned short* qh1 = &Qhs[((wave << 5) + 16) * 32];
    unsigned short* ql0 = &Qls[(wave << 5) * 32]; unsigned short* ql1 = &Qls[((wave << 5) + 16) * 32];
    unsigned short* kh0 = &Khs[(wave << 5) * 32]; unsigned short* kh1 = &Khs[((wave << 5) + 16) * 32];
    unsigned short* kl0 = &Kls[(wave << 5) * 32]; unsigned short* kl1 = &Kls[((wave << 5) + 16) * 32];

    float* dz = &diagw[0][0];
    dz[tid] = 0.f; dz[tid + 256] = 0.f; dz[tid + 512] = 0.f; dz[tid + 768] = 0.f;

    const int la = lane & 15, h4 = lane >> 4;
    f32x4 acc[4][4] = {};

    for (int k0 = 0; k0 < 512; k0 += 32) {
        gld16(Qh + g0 + k0, qh0); gld16(Qh + g1 + k0, qh1);
        gld16(Ql + g0 + k0, ql0); gld16(Ql + g1 + k0, ql1);
        gld16(Kh + p0 + k0, kh0); gld16(Kh + p1 + k0, kh1);
        gld16(Kl + p0 + k0, kl0); gld16(Kl + p1 + k0, kl1);
        __syncthreads();
        bf16x8 ah[4], al[4], bh[4], bl[4];
#pragma unroll
        for (int i = 0; i < 4; ++i) {
            int ro = (wm + i * 16 + la) * 32 + h4 * 8;
            int co = (wn + i * 16 + la) * 32 + h4 * 8;
            ah[i] = *(const bf16x8*)&Qhs[ro];
            al[i] = *(const bf16x8*)&Qls[ro];
            bh[i] = *(const bf16x8*)&Khs[co];
            bl[i] = *(const bf16x8*)&Kls[co];
        }
#pragma unroll
        for (int mi = 0; mi < 4; ++mi)
#pragma unroll
            for (int ni = 0; ni < 4; ++ni) {
                acc[mi][ni] = __builtin_amdgcn_mfma_f32_16x16x32_bf16(ah[mi], bh[ni], acc[mi][ni], 0, 0, 0);
                acc[mi][ni] = __builtin_amdgcn_mfma_f32_16x16x32_bf16(ah[mi], bl[ni], acc[mi][ni], 0, 0, 0);
                acc[mi][ni] = __builtin_amdgcn_mfma_f32_16x16x32_bf16(al[mi], bh[ni], acc[mi][ni], 0, 0, 0);
            }
        __syncthreads();
    }

    // register pre-reduction: frags with equal d = mi-ni share diag bins
    float rbin[7][4] = {};
#pragma unroll
    for (int mi = 0; mi < 4; ++mi)
#pragma unroll
        for (int ni = 0; ni < 4; ++ni)
#pragma unroll
            for (int r = 0; r < 4; ++r)
                rbin[mi - ni + 3][r] += acc[mi][ni][r];

    const int base = (wm - wn) + 4 * h4 - la + 127;
#pragma unroll
    for (int d = 0; d < 7; ++d)
#pragma unroll
        for (int r = 0; r < 4; ++r)
            atomicAdd(&diagw[wave][base + 16 * (d - 3) + r], rbin[d][r]);
    __syncthreads();
    if (tid < 255) {
        float s = diagw[0][tid] + diagw[1][tid] + diagw[2][tid] + diagw[3][tid];
        int n = (bt - bs + tid - 127) & 1023;
        atomicAdd(&G[(b << 10) + n], s);
    }
}

// ---------------------------------------------------------------------------
// Per-batch top-20 + softmax, parallel argmax (tie -> lowest index).
// ---------------------------------------------------------------------------
__global__ __launch_bounds__(256)
void topk_kernel(const float* __restrict__ G, int* __restrict__ delay,
                 float* __restrict__ tc)
{
    __shared__ float vals[1024];
    __shared__ float pw[4];
    __shared__ int   pwi[4];
    __shared__ float wsel[TOPK_];
    __shared__ int   isel[TOPK_];
    const int b = blockIdx.x, tid = threadIdx.x;
    const int lane = tid & 63, wid = tid >> 6;
    for (int i = tid; i < 1024; i += 256) vals[i] = G[(b << 10) + i] * (1.0f / 512.0f);
    __syncthreads();
    for (int it = 0; it < TOPK_; ++it) {
        float bv = -INFINITY; int bi = 0;
#pragma unroll
        for (int u = 0; u < 4; ++u) {
            int i = tid * 4 + u;
            float v = vals[i];
            if (v > bv) { bv = v; bi = i; }
        }
#pragma unroll
        for (int o = 32; o > 0; o >>= 1) {
            float ov = __shfl_xor(bv, o, 64);
            int   oi = __shfl_xor(bi, o, 64);
            if (ov > bv || (ov == bv && oi < bi)) { bv = ov; bi = oi; }
        }
        if (lane == 0) { pw[wid] = bv; pwi[wid] = bi; }
        __syncthreads();
        if (tid == 0) {
            float m = pw[0]; int mi = pwi[0];
#pragma unroll
            for (int t = 1; t < 4; ++t)
                if (pw[t] > m || (pw[t] == m && pwi[t] < mi)) { m = pw[t]; mi = pwi[t]; }
            wsel[it] = m; isel[it] = mi;
            vals[mi] = -INFINITY;
        }
        __syncthreads();
    }
    if (tid == 0) {
        float m = wsel[0];
#pragma unroll
        for (int i = 1; i < TOPK_; ++i) m = fmaxf(m, wsel[i]);
        float e[TOPK_], s = 0.f;
#pragma unroll
        for (int i = 0; i < TOPK_; ++i) { e[i] = expf(wsel[i] - m); s += e[i]; }
        float inv = 1.0f / s;
#pragma unroll
        for (int i = 0; i < TOPK_; ++i) {
            tc[b * TOPK_ + i] = e[i] * inv;
            delay[b * TOPK_ + i] = isel[i];
        }
    }
}

// out[b,l,d] = sum_i tc[b,i] * V[b,(l+delay)%1024,d], bf16 in/out, 8-wide
__global__ void agg_kernel(const unsigned short* __restrict__ V, const int* __restrict__ delay,
                           const float* __restrict__ tc, unsigned short* __restrict__ out)
{
    int idx = (blockIdx.x * blockDim.x + threadIdx.x) * 8;
    int d = idx & 511;
    int l = (idx >> 9) & 1023;
    int b = idx >> 19;
    const unsigned short* Vb = V + ((size_t)b << 19);
    float s[8] = {};
#pragma unroll
    for (int i = 0; i < TOPK_; ++i) {
        int row = (l + delay[b * TOPK_ + i]) & 1023;
        float w = tc[b * TOPK_ + i];
        u16x8 v = *(const u16x8*)&Vb[((size_t)row << 9) + d];
#pragma unroll
        for (int j = 0; j < 8; ++j)
            s[j] = fmaf(w, bf2f(v[j]), s[j]);
    }
    u16x8 o;
#pragma unroll
    for (int j = 0; j < 8; ++j) o[j] = f2bf(s[j]);
    *(u16x8*)&out[idx] = o;
}

// ---------------------------------------------------------------------------
// series_decomp with optional bf16 dual-out of the seasonal part.
// ---------------------------------------------------------------------------
__global__ void decomp_kernel(const float* __restrict__ x, float* __restrict__ seas,
                              unsigned short* __restrict__ seasb,
                              float* __restrict__ trend, int Bn, int Ln, int Ch,
                              int nseg, int tmode)
{
    int idx = blockIdx.x * blockDim.x + threadIdx.x;
    int total = Bn * Ch * nseg;
    if (idx >= total) return;
    int ch = idx % Ch;
    int rest = idx / Ch;
    int seg = rest % nseg;
    int b = rest / nseg;
    int segL = Ln / nseg;
    int l0 = seg * segL;
    const float* xp = x + (size_t)b * Ln * Ch + ch;
    float* sp = seas + (size_t)b * Ln * Ch + ch;
    unsigned short* bp = seasb ? seasb + (size_t)b * Ln * Ch + ch : nullptr;
    float* tp = trend ? trend + (size_t)b * Ln * Ch + ch : nullptr;
    float s = 0.f;
    for (int j = -12; j <= 12; ++j) {
        int t = l0 + j;
        t = t < 0 ? 0 : (t > Ln - 1 ? Ln - 1 : t);
        s += xp[(size_t)t * Ch];
    }
    for (int l = l0; l < l0 + segL; ++l) {
        float mm = s * (1.0f / 25.0f);
        float v = xp[(size_t)l * Ch] - mm;
        sp[(size_t)l * Ch] = v;
        if (bp) bp[(size_t)l * Ch] = f2bf(v);
        if (tmode == 1) tp[(size_t)l * Ch] = mm;
        else if (tmode == 2) tp[(size_t)l * Ch] += mm;
        int ta = l + 13; if (ta > Ln - 1) ta = Ln - 1;
        int ts = l - 12; if (ts < 0) ts = 0;
        s += xp[(size_t)ta * Ch] - xp[(size_t)ts * Ch];
    }
}

__global__ __launch_bounds__(256)
void lnrow_kernel(const float* __restrict__ x, const float* __restrict__ g,
                  const float* __restrict__ bv, float* __restrict__ out)
{
    __shared__ float sh1[4], sh2[4];
    int row = blockIdx.x, tid = threadIdx.x;
    const float* xr = x + ((size_t)row << 9);
    float v0 = xr[tid], v1 = xr[tid + 256];
    float s = v0 + v1, q = v0 * v0 + v1 * v1;
#pragma unroll
    for (int o = 32; o > 0; o >>= 1) {
        s += __shfl_down(s, o, 64);
        q += __shfl_down(q, o, 64);
    }
    int wid = tid >> 6;
    if ((tid & 63) == 0) { sh1[wid] = s; sh2[wid] = q; }
    __syncthreads();
    if (tid == 0) {
        sh1[0] = sh1[0] + sh1[1] + sh1[2] + sh1[3];
        sh2[0] = sh2[0] + sh2[1] + sh2[2] + sh2[3];
    }
    __syncthreads();
    float mu = sh1[0] * (1.0f / 512.0f);
    float var = sh2[0] * (1.0f / 512.0f) - mu * mu;
    float inv = rsqrtf(var + 1e-5f);
    out[((size_t)row << 9) + tid] = (v0 - mu) * inv * g[tid] + bv[tid];
    out[((size_t)row << 9) + tid + 256] = (v1 - mu) * inv * g[tid + 256] + bv[tid + 256];
}

__global__ void colmean_kernel(const float* __restrict__ x, float* __restrict__ m)
{
    int idx = blockIdx.x * blockDim.x + threadIdx.x;
    if (idx >= B_ * D_) return;
    int b = idx >> 9, d = idx & 511;
    const float* xp = x + ((size_t)b << 19) + d;
    float s = 0.f;
    for (int l = 0; l < L_; ++l) s += xp[(size_t)l << 9];
    m[idx] = s * (1.0f / 1024.0f);
}

// out_bf16 = x - colmean (encoder output, bf16 only)
__global__ void colsub_kernel(const float* __restrict__ x, const float* __restrict__ m,
                              unsigned short* __restrict__ out)
{
    int idx = blockIdx.x * blockDim.x + threadIdx.x;
    int d = idx & 511;
    int b = idx >> 19;
    out[idx] = f2bf(x[idx] - m[(b << 9) + d]);
}

__global__ void meanx_kernel(const float* __restrict__ x, float* __restrict__ m)
{
    int idx = blockIdx.x * blockDim.x + threadIdx.x;
    if (idx >= B_ * C_) return;
    int b = idx >> 6, c = idx & 63;
    const float* xp = x + (size_t)b * L_ * C_ + c;
    float s = 0.f;
    for (int l = 0; l < L_; ++l) s += xp[(size_t)l << 6];
    m[idx] = s * (1.0f / 1024.0f);
}

__global__ void builddec_kernel(const float* __restrict__ trenc, const float* __restrict__ seenc,
                                const float* __restrict__ meanc,
                                float* __restrict__ trend, float* __restrict__ seasin)
{
    int idx = blockIdx.x * blockDim.x + threadIdx.x;
    int c = idx & 63;
    int l = (idx >> 6) & 1023;
    int b = idx >> 16;
    if (l < 512) {
        int src = (b << 16) + ((512 + l) << 6) + c;
        trend[idx] = trenc[src];
        seasin[idx] = seenc[src];
    } else {
        trend[idx] = meanc[(b << 6) + c];
        seasin[idx] = 0.f;
    }
}

__global__ void final_kernel(const float* __restrict__ trend, const float* __restrict__ s64,
                             float* __restrict__ out)
{
    int idx = blockIdx.x * blockDim.x + threadIdx.x;
    int c = idx & 63;
    int l = (idx >> 6) & 511;
    int b = idx >> 15;
    int src = (b << 16) + ((512 + l) << 6) + c;
    out[idx] = trend[src] + s64[src];
}

__global__ void zero_kernel(float* __restrict__ p, int n)
{
    int idx = blockIdx.x * blockDim.x + threadIdx.x;
    if (idx < n) p[idx] = 0.f;
}

// ---------------------------------------------------------------------------
extern "C" void kernel_launch(void* const* d_in, const int* in_sizes, int n_in,
                              void* d_out, int out_size, void* d_ws, size_t ws_size,
                              hipStream_t stream)
{
    auto F = [&](int i) { return (const float*)d_in[i]; };
    const float* x_enc     = F(0);
    const float* enc_emb_w = F(2);
    const float* dec_emb_w = F(3);
    const float* enc_Wq = F(4);  const float* enc_bq = F(5);
    const float* dsa_Wq = F(6);  const float* dsa_bq = F(7);
    const float* dca_Wq = F(8);  const float* dca_bq = F(9);
    const float* enc_Wk = F(10); const float* enc_bk = F(11);
    const float* dsa_Wk = F(12); const float* dsa_bk = F(13);
    const float* dca_Wk = F(14); const float* dca_bk = F(15);
    const float* enc_Wv = F(16); const float* enc_bv = F(17);
    const float* dsa_Wv = F(18); const float* dsa_bv = F(19);
    const float* dca_Wv = F(20); const float* dca_bv = F(21);
    const float* enc_Wo = F(22); const float* enc_bo = F(23);
    const float* dsa_Wo = F(24); const float* dsa_bo = F(25);
    const float* dca_Wo = F(26); const float* dca_bo = F(27);
    const float* enc_ff1 = F(28); const float* enc_ff2 = F(29);
    const float* enc_ng = F(30);  const float* enc_nb = F(31);
    const float* dec_ff1 = F(32); const float* dec_ff2 = F(33);
    const float* dec_trend_w = F(34);
    const float* proj_w = F(35);  const float* proj_b = F(36);

    constexpr size_t F512 = (size_t)B_ * L_ * D_;   // 8388608
    constexpr size_t F64  = (size_t)B_ * L_ * C_;   // 1048576
    constexpr size_t SMALL = 1024 + 16384 + 320 + 320 + 8192;
    constexpr size_t WTSN = 2 * 1024 * 1024;        // bf16 weight scratch elems
    size_t need = (3 * F512 + 2 * F64 + SMALL) * 4 + (8 * F512 + WTSN) * 2;
    if (ws_size < need) return;

    float* X      = (float*)d_ws;
    float* T1     = X + F512;
    float* TSUM   = T1 + F512;
    float* SEASIN = TSUM + F512;
    float* TREND  = SEASIN + F64;
    float* MEANC  = TREND + F64;
    float* G      = MEANC + 1024;
    float* TCW    = G + 16384;
    int*   DEL    = (int*)(TCW + 320);
    float* LNMEAN = (float*)(DEL + 320);
    unsigned short* AB  = (unsigned short*)(LNMEAN + 8192);
    unsigned short* EB  = AB + F512;
    unsigned short* VB  = EB + F512;
    unsigned short* HB  = VB + F512;
    unsigned short* QHI = HB + F512;
    unsigned short* QLO = QHI + F512;
    unsigned short* KHI = QLO + F512;
    unsigned short* KLO = KHI + F512;
    unsigned short* WTS = KLO + F512;
    float* OUT = (float*)d_out;

    const int M = B_ * L_;  // 16384

    auto mgemm = [&](const unsigned short* A, const unsigned short* Bt, float* Cf,
                     unsigned short* Cb, unsigned short* Cl, const float* bias,
                     int Mm, int Nn, int Kk, int flags) {
        int nx = Nn / 128;
        int total = nx * (Mm / 128);
        gemm_bf16<<<total, 256, 0, stream>>>(A, Bt, Cf, Cb, Cl, bias, Mm, Nn, Kk, flags, nx);
    };
    auto cgemm = [&](const float* A, const float* Wt, float* Cm, unsigned short* Cb,
                     const float* bias, int Mm, int Nn, int Kk, int flags, int taps) {
        dim3 g(Nn / GBN, Mm / GBM);
        conv_gemm_f32<<<g, 256, 0, stream>>>(A, Wt, Cm, Cb, bias, Mm, Nn, Kk, flags, taps);
    };
    auto tcast = [&](const float* W, unsigned short* Wt, int R, int Cc) {
        tcast_kernel<<<dim3(Cc / 32, R / 32), 256, 0, stream>>>(W, Wt, R, Cc);
    };
    auto attn = [&](const unsigned short* qin, const unsigned short* kvin,
                    const float* Wq, const float* bq, const float* Wk, const float* bk,
                    const float* Wv, const float* bvp, const float* Wo, const float* bo,
                    float* resid) {
        unsigned short* Wt0 = WTS;
        unsigned short* Wt1 = WTS + 262144;
        unsigned short* Wt2 = WTS + 524288;
        unsigned short* Wt3 = WTS + 786432;
        tcast(Wq, Wt0, 512, 512);
        tcast(Wk, Wt1, 512, 512);
        tcast(Wv, Wt2, 512, 512);
        tcast(Wo, Wt3, 512, 512);
        mgemm(qin,  Wt0, nullptr, QHI, QLO, bq, M, 512, 512, 0);
        mgemm(kvin, Wt1, nullptr, KHI, KLO, bk, M, 512, 512, 0);
        mgemm(kvin, Wt2, nullptr, VB, nullptr, bvp, M, 512, 512, 0);
        zero_kernel<<<16384 / 256, 256, 0, stream>>>(G, 16384);
        corr_mfma<<<dim3(8, 8, 16), 256, 0, stream>>>(QHI, QLO, KHI, KLO, G);
        topk_kernel<<<16, 256, 0, stream>>>(G, DEL, TCW);
        agg_kernel<<<(int)(F512 / 8 / 256), 256, 0, stream>>>(VB, DEL, TCW, HB);
        mgemm(HB, Wt3, resid, nullptr, nullptr, bo, M, 512, 512, 1);
    };
    auto ffblock = [&](const unsigned short* xin, const float* W1, const float* W2, float* resid) {
        unsigned short* Wf1 = WTS;
        unsigned short* Wf2 = WTS + 1048576;
        tcast(W1, Wf1, 512, 2048);
        tcast(W2, Wf2, 2048, 512);
        for (int c = 0; c < 4; ++c) {
            mgemm(xin + (size_t)c * 4096 * 512, Wf1, nullptr, HB, nullptr, nullptr, 4096, 2048, 512, 2);
            mgemm(HB, Wf2, resid + (size_t)c * 4096 * 512, nullptr, nullptr, nullptr, 4096, 512, 2048, 1);
        }
    };

    // ---------------- prep: decomposition of x_enc, decoder inits -----------
    float* SEENC = (float*)QHI;   // aliases: prep phase only
    float* TRENC = SEENC + F64;
    decomp_kernel<<<(B_ * C_ * 64 + 255) / 256, 256, 0, stream>>>(x_enc, SEENC, nullptr, TRENC, B_, L_, C_, 64, 1);
    meanx_kernel<<<(B_ * C_ + 255) / 256, 256, 0, stream>>>(x_enc, MEANC);
    builddec_kernel<<<(int)(F64 / 256), 256, 0, stream>>>(TRENC, SEENC, MEANC, TREND, SEASIN);

    // ---------------- encoder ----------------------------------------------
    cgemm(x_enc, enc_emb_w, X, AB, nullptr, M, D_, C_, 4, 3);

    for (int l = 0; l < 2; ++l) {
        attn(AB, AB,
             enc_Wq + (size_t)l * D_ * D_, enc_bq + l * D_,
             enc_Wk + (size_t)l * D_ * D_, enc_bk + l * D_,
             enc_Wv + (size_t)l * D_ * D_, enc_bv + l * D_,
             enc_Wo + (size_t)l * D_ * D_, enc_bo + l * D_, X);
        decomp_kernel<<<(B_ * D_ * 64 + 255) / 256, 256, 0, stream>>>(X, T1, AB, nullptr, B_, L_, D_, 64, 0);
        ffblock(AB, enc_ff1 + (size_t)l * D_ * DFF_, enc_ff2 + (size_t)l * DFF_ * D_, T1);
        decomp_kernel<<<(B_ * D_ * 64 + 255) / 256, 256, 0, stream>>>(T1, X, AB, nullptr, B_, L_, D_, 64, 0);
    }
    lnrow_kernel<<<M, 256, 0, stream>>>(X, enc_ng, enc_nb, T1);
    colmean_kernel<<<(B_ * D_ + 255) / 256, 256, 0, stream>>>(T1, LNMEAN);
    colsub_kernel<<<(int)(F512 / 256), 256, 0, stream>>>(T1, LNMEAN, EB);

    // ---------------- decoder ----------------------------------------------
    float* XD = X;
    cgemm(SEASIN, dec_emb_w, XD, AB, nullptr, M, D_, C_, 4, 3);

    attn(AB, AB, dsa_Wq, dsa_bq, dsa_Wk, dsa_bk, dsa_Wv, dsa_bv, dsa_Wo, dsa_bo, XD);
    decomp_kernel<<<(B_ * D_ * 64 + 255) / 256, 256, 0, stream>>>(XD, T1, AB, TSUM, B_, L_, D_, 64, 1);

    attn(AB, EB, dca_Wq, dca_bq, dca_Wk, dca_bk, dca_Wv, dca_bv, dca_Wo, dca_bo, T1);
    decomp_kernel<<<(B_ * D_ * 64 + 255) / 256, 256, 0, stream>>>(T1, XD, AB, TSUM, B_, L_, D_, 64, 2);

    ffblock(AB, dec_ff1, dec_ff2, XD);
    decomp_kernel<<<(B_ * D_ * 64 + 255) / 256, 256, 0, stream>>>(XD, T1, nullptr, TSUM, B_, L_, D_, 64, 2);

    // trend projection conv (3 taps, fused) accumulated onto TREND
    cgemm(TSUM, dec_trend_w, TREND, nullptr, nullptr, M, C_, D_, 1, 3);

    // seasonal projection + final output
    float* S64 = (float*)QHI;  // free by now
    cgemm(T1, proj_w, S64, nullptr, proj_b, M, C_, D_, 0, 1);
    final_kernel<<<(B_ * 512 * C_) / 256, 256, 0, stream>>>(TREND, S64, OUT);
}